// Round 4
// baseline (492.714 us; speedup 1.0000x reference)
//
#include <hip/hip_runtime.h>
#include <hip/hip_bf16.h>

#define NND 6890
#define NED 41340

typedef __bf16 bf16x8 __attribute__((ext_vector_type(8)));
typedef float f32x4 __attribute__((ext_vector_type(4)));
typedef unsigned short u16x4 __attribute__((ext_vector_type(4)));
typedef unsigned short u16x8 __attribute__((ext_vector_type(8)));

__device__ inline unsigned short f32_bf16(float f) {
  unsigned int u = __float_as_uint(f);
  unsigned int r = (u + 0x7FFFu + ((u >> 16) & 1u)) >> 16;
  return (unsigned short)r;
}
__device__ inline void split2(float v, unsigned short& hi, unsigned short& lo) {
  unsigned short h = f32_bf16(v);
  float hf = __uint_as_float((unsigned int)h << 16);
  hi = h;
  lo = f32_bf16(v - hf);
}
__device__ inline float elu_f(float v) { return v > 0.f ? v : (expf(v) - 1.f); }

__device__ __forceinline__ void gload_lds16(const void* g, void* l) {
  __builtin_amdgcn_global_load_lds((const __attribute__((address_space(1))) void*)g,
                                   (__attribute__((address_space(3))) void*)l, 16, 0, 0);
}

__global__ void zero_int_kernel(int* p, int n) {
  int i = blockIdx.x * blockDim.x + threadIdx.x;
  if (i < n) p[i] = 0;
}

__global__ void edge_prep_kernel(const int* __restrict__ erow, const float* __restrict__ pseudo,
                                 float* __restrict__ ew, int* __restrict__ ek,
                                 int* __restrict__ deg, int E) {
  int e = blockIdx.x * blockDim.x + threadIdx.x;
  if (e >= E) return;
  float p0 = pseudo[2 * e + 0] * 4.0f;
  float p1 = pseudo[2 * e + 1] * 4.0f;
  int i0 = (int)floorf(p0); i0 = i0 < 0 ? 0 : (i0 > 3 ? 3 : i0);
  int i1 = (int)floorf(p1); i1 = i1 < 0 ? 0 : (i1 > 3 ? 3 : i1);
  float f0 = p0 - (float)i0, f1 = p1 - (float)i1;
  ew[4 * e + 0] = (1.f - f0) * (1.f - f1);
  ew[4 * e + 1] = f0 * (1.f - f1);
  ew[4 * e + 2] = (1.f - f0) * f1;
  ew[4 * e + 3] = f0 * f1;
  int b = i0 + 5 * i1;
  ek[4 * e + 0] = b; ek[4 * e + 1] = b + 1; ek[4 * e + 2] = b + 5; ek[4 * e + 3] = b + 6;
  atomicAdd(&deg[erow[e]], 1);
}

__global__ void scan_kernel(const int* __restrict__ deg, int* __restrict__ rowptr,
                            int* __restrict__ cursor, float* __restrict__ deginv, int n) {
  __shared__ int part[1024];
  int t = threadIdx.x;
  int CH = (n + 1023) >> 10;
  int base = t * CH;
  int s = 0;
  for (int j = 0; j < CH; ++j) { int i = base + j; if (i < n) s += deg[i]; }
  part[t] = s;
  __syncthreads();
  for (int off = 1; off < 1024; off <<= 1) {
    int v = (t >= off) ? part[t - off] : 0;
    __syncthreads();
    part[t] += v;
    __syncthreads();
  }
  int run = (t == 0) ? 0 : part[t - 1];
  for (int j = 0; j < CH; ++j) {
    int i = base + j;
    if (i < n) {
      rowptr[i] = run; cursor[i] = run;
      int d = deg[i];
      deginv[i] = 1.0f / fmaxf((float)d, 1.0f);
      run += d;
    }
  }
  if (t == 1023) rowptr[n] = part[1023];
}

__global__ void csr_fill_kernel(const int* __restrict__ erow, int* __restrict__ cursor,
                                int* __restrict__ csr, int E) {
  int e = blockIdx.x * blockDim.x + threadIdx.x;
  if (e >= E) return;
  int slot = atomicAdd(&cursor[erow[e]], 1);
  csr[slot] = e;
}

// B[r, k*Fin+i] = deginv[r] * sum_{edges into r} w[e,s(k)] * x[col[e], i]; last Fin cols = x[r]
// Barrier-free inner loop: LDS f32 atomics (within an edge all (k,i) are distinct).
__global__ void b_build_kernel(const float* __restrict__ x, const int* __restrict__ ecol,
                               const float* __restrict__ ew, const int* __restrict__ ek,
                               const int* __restrict__ rowptr, const int* __restrict__ csr,
                               const float* __restrict__ deginv,
                               float* __restrict__ B, int Fin) {
  extern __shared__ float lds[];  // 26*Fin floats
  int r = blockIdx.x;
  int T = blockDim.x;  // 4*Fin
  int tid = threadIdx.x;
  int nb = 25 * Fin;
  for (int j = tid; j < nb; j += T) lds[j] = 0.f;
  if (tid < Fin) lds[nb + tid] = x[(size_t)r * Fin + tid];
  __syncthreads();
  int p0 = rowptr[r], p1 = rowptr[r + 1];
  int s = tid / Fin;
  int i = tid - s * Fin;
  for (int p = p0; p < p1; ++p) {
    int e = csr[p];
    int c = ecol[e];
    float wv = ew[4 * e + s];
    int k = ek[4 * e + s];
    float xv = x[(size_t)c * Fin + i];
    atomicAdd(&lds[k * Fin + i], wv * xv);
  }
  __syncthreads();
  float dinv = deginv[r];
  int tot = nb + Fin;
  for (int j = tid; j < tot; j += T) {
    float v = lds[j];
    if (j < nb) v *= dinv;
    B[(size_t)r * tot + j] = v;
  }
}

// All weight splits (hi/lo bf16, transposed to [F, ldt]) in one kernel.
__global__ void weights_prep_kernel(const float* __restrict__ W_lin, const float* __restrict__ w1,
                                    const float* __restrict__ r1, const float* __restrict__ w2,
                                    const float* __restrict__ r2, const float* __restrict__ w3,
                                    const float* __restrict__ r3, const float* __restrict__ W1,
                                    unsigned short* __restrict__ Th, unsigned short* __restrict__ Tl) {
  const int tstart[9] = {0, 17, 30, 31, 81, 83, 283, 291, 323};
  const int jK[8]    = {544, 400, 16, 800, 32, 1600, 64, 128};
  const int jF[8]    = {16, 32, 32, 64, 64, 128, 128, 256};
  const int jldt[8]  = {544, 416, 416, 832, 832, 1664, 1664, 128};
  const int jkoff[8] = {0, 0, 400, 0, 800, 0, 1600, 0};
  const int jdst[8]  = {0, 8704, 8704, 22016, 22016, 75264, 75264, 288256};
  int b = blockIdx.x;
  int job = 0;
  while (job < 7 && b >= tstart[job + 1]) ++job;
  int t = b - tstart[job];
  int fxc = (jF[job] + 31) >> 5;
  int kt = t / fxc, ft = t % fxc;
  const float* src;
  switch (job) {
    case 0: src = W_lin; break;
    case 1: src = w1; break;
    case 2: src = r1; break;
    case 3: src = w2; break;
    case 4: src = r2; break;
    case 5: src = w3; break;
    case 6: src = r3; break;
    default: src = W1; break;
  }
  int K = jK[job], F = jF[job], ldt = jldt[job], koff = jkoff[job];
  unsigned short* th = Th + jdst[job];
  unsigned short* tl = Tl + jdst[job];
  int k0 = kt * 32, c0 = ft * 32;
  __shared__ float tbuf[32][33];
  int tx = threadIdx.x & 31, ty = threadIdx.x >> 5;  // 32 x 8
  for (int j = ty; j < 32; j += 8) {
    int gk = k0 + j, gc = c0 + tx;
    tbuf[j][tx] = (gk < K && gc < F) ? src[(size_t)gk * F + gc] : 0.f;
  }
  __syncthreads();
  for (int j = ty; j < 32; j += 8) {
    int gc = c0 + j, gk = k0 + tx;
    if (gc < F && gk < K) {
      unsigned short h, lo2;
      split2(tbuf[tx][j], h, lo2);
      th[(size_t)gc * ldt + koff + gk] = h;
      tl[(size_t)gc * ldt + koff + gk] = lo2;
    }
  }
}

// Partial GEMM (bf16x3 split) over K-slice z: P[z][M][F] = A @ W (no bias/elu).
template <int BN>
__global__ __launch_bounds__(256) void gemm_x3_partial_kernel(
    const float* __restrict__ A, const unsigned short* __restrict__ Wth,
    const unsigned short* __restrict__ Wtl, float* __restrict__ P,
    int M, int Kd, int F, int KS) {
  constexpr int BK = 32;
  constexpr int NF = BN / 16;
  constexpr int WU = (BK * BN) / 4;
  constexpr int WREP = (WU + 255) / 256;
  __shared__ __align__(16) unsigned short Ah[2][64][40];
  __shared__ __align__(16) unsigned short Al[2][64][40];
  __shared__ __align__(16) unsigned short Wh[2][BN][40];
  __shared__ __align__(16) unsigned short Wl[2][BN][40];
  int tid = threadIdx.x;
  int wave = tid >> 6, lane = tid & 63;
  int g = lane >> 4, r = lane & 15;
  int row0 = blockIdx.y * 64;
  int col0 = blockIdx.x * BN;
  int z = blockIdx.z;
  int nt = Kd >> 5;
  int ta = z * nt / KS, tb = (z + 1) * nt / KS;

  f32x4 acc[NF];
#pragma unroll
  for (int n = 0; n < NF; ++n)
#pragma unroll
    for (int q = 0; q < 4; ++q) acc[n][q] = 0.f;

  f32x4 ra[2];
  u16x4 rwh[WREP], rwl[WREP];

  auto loadTiles = [&](int kb) {
#pragma unroll
    for (int rep = 0; rep < 2; ++rep) {
      int u = tid + rep * 256;
      int rr = u >> 3, kq = (u & 7) * 4;
      int gr = row0 + rr;
      f32x4 v = {0.f, 0.f, 0.f, 0.f};
      if (gr < M) v = *(const f32x4*)(A + (size_t)gr * Kd + kb + kq);
      ra[rep] = v;
    }
#pragma unroll
    for (int rep = 0; rep < WREP; ++rep) {
      int u = tid + rep * 256;
      if (u < WU) {
        int cc = u >> 3, kq = (u & 7) * 4;
        rwh[rep] = *(const u16x4*)(Wth + (size_t)(col0 + cc) * Kd + kb + kq);
        rwl[rep] = *(const u16x4*)(Wtl + (size_t)(col0 + cc) * Kd + kb + kq);
      }
    }
  };
  auto writeLDS = [&](int buf) {
#pragma unroll
    for (int rep = 0; rep < 2; ++rep) {
      int u = tid + rep * 256;
      int rr = u >> 3, kq = (u & 7) * 4;
      u16x4 h, l;
#pragma unroll
      for (int j = 0; j < 4; ++j) {
        unsigned short hh, ll;
        split2(ra[rep][j], hh, ll);
        h[j] = hh; l[j] = ll;
      }
      *(u16x4*)&Ah[buf][rr][kq] = h;
      *(u16x4*)&Al[buf][rr][kq] = l;
    }
#pragma unroll
    for (int rep = 0; rep < WREP; ++rep) {
      int u = tid + rep * 256;
      if (u < WU) {
        int cc = u >> 3, kq = (u & 7) * 4;
        *(u16x4*)&Wh[buf][cc][kq] = rwh[rep];
        *(u16x4*)&Wl[buf][cc][kq] = rwl[rep];
      }
    }
  };

  int n = tb - ta;
  loadTiles(ta * BK);
  writeLDS(0);
  __syncthreads();
  for (int tt = 0; tt < n; ++tt) {
    int cur = tt & 1;
    if (tt + 1 < n) loadTiles((ta + tt + 1) * BK);
    bf16x8 fah = *(const bf16x8*)&Ah[cur][wave * 16 + r][g * 8];
    bf16x8 fal = *(const bf16x8*)&Al[cur][wave * 16 + r][g * 8];
#pragma unroll
    for (int nn = 0; nn < NF; ++nn) {
      bf16x8 fbh = *(const bf16x8*)&Wh[cur][nn * 16 + r][g * 8];
      bf16x8 fbl = *(const bf16x8*)&Wl[cur][nn * 16 + r][g * 8];
      acc[nn] = __builtin_amdgcn_mfma_f32_16x16x32_bf16(fah, fbh, acc[nn], 0, 0, 0);
      acc[nn] = __builtin_amdgcn_mfma_f32_16x16x32_bf16(fal, fbh, acc[nn], 0, 0, 0);
      acc[nn] = __builtin_amdgcn_mfma_f32_16x16x32_bf16(fah, fbl, acc[nn], 0, 0, 0);
    }
    if (tt + 1 < n) writeLDS(cur ^ 1);
    __syncthreads();
  }
#pragma unroll
  for (int nn = 0; nn < NF; ++nn) {
    int gc = col0 + nn * 16 + r;
#pragma unroll
    for (int q = 0; q < 4; ++q) {
      int gr = row0 + wave * 16 + g * 4 + q;
      if (gr < M) P[((size_t)z * M + gr) * F + gc] = acc[nn][q];
    }
  }
}

// out = elu(sum_z P[z] + bias); f32 or bf16 out
__global__ __launch_bounds__(256) void combine_elu_kernel(
    const float* __restrict__ P, const float* __restrict__ bias,
    float* __restrict__ outF, unsigned short* __restrict__ outB,
    int M, int F, int KS) {
  int i4 = blockIdx.x * 256 + threadIdx.x;
  int fv = F >> 2;
  int total = M * fv;
  if (i4 >= total) return;
  int gr = i4 / fv, c4 = (i4 - gr * fv) * 4;
  f32x4 s = {0.f, 0.f, 0.f, 0.f};
  for (int z = 0; z < KS; ++z)
    s += *(const f32x4*)(P + ((size_t)z * M + gr) * F + c4);
  f32x4 bv = *(const f32x4*)(bias + c4);
#pragma unroll
  for (int j = 0; j < 4; ++j) s[j] = elu_f(s[j] + bv[j]);
  if (outB) {
    u16x4 o;
#pragma unroll
    for (int j = 0; j < 4; ++j) o[j] = f32_bf16(s[j]);
    *(u16x4*)(outB + (size_t)gr * F + c4) = o;
  } else {
    *(f32x4*)(outF + (size_t)gr * F + c4) = s;
  }
}

// W2 [K=256, N] f32  ->  Wt [N, K] bf16
__global__ void w2_cast_transpose_kernel(const float* __restrict__ W2,
                                         unsigned short* __restrict__ Wt, int K, int N) {
  __shared__ float t[32][33];
  int c0 = blockIdx.x * 32, k0 = blockIdx.y * 32;
  int tx = threadIdx.x, ty = threadIdx.y;  // 32 x 8
  for (int j = ty; j < 32; j += 8) {
    int gk = k0 + j, gc = c0 + tx;
    t[j][tx] = (gk < K && gc < N) ? W2[(size_t)gk * N + gc] : 0.f;
  }
  __syncthreads();
  for (int j = ty; j < 32; j += 8) {
    int gc = c0 + j, gk = k0 + tx;
    if (gc < N && gk < K) Wt[(size_t)gc * K + gk] = f32_bf16(t[tx][j]);
  }
}

// Final layer GEMM, full-K LDS residency, XOR-swizzled, global_load_lds staging,
// swapped-operand MFMA (lane holds a row in r, 4 consecutive cols per g).
// MODE 0: emit per-(row, 32-col-half) online-softmax partials (m, s) -> stats.
// MODE 1: write out[gr][gc] = logit - lse[gr].
template <int MODE>
__global__ __launch_bounds__(256) void gemm_final_kernel(
    const unsigned short* __restrict__ A, const unsigned short* __restrict__ Bt,
    const float* __restrict__ bias, const float* __restrict__ lse,
    float* __restrict__ outp, int M, int N) {
  __shared__ __align__(16) unsigned short lds[2][64][256];  // 64 KB
  int tid = threadIdx.x;
  int w = tid >> 6, l = tid & 63;
  int row0 = blockIdx.y * 64, col0 = blockIdx.x * 64;
  {
    int half = l >> 5;
    int c = l & 31;
#pragma unroll
    for (int i = 0; i < 8; ++i) {
      int rb = w * 16 + i * 2;
      int rr = rb + half;
      int gra = row0 + rr; if (gra >= M) gra = M - 1;
      int grb = col0 + rr; if (grb >= N) grb = N - 1;
      int cs = ((c ^ (rr & 7)) << 3);
      gload_lds16(A + (size_t)gra * 256 + cs, &lds[0][rb][0]);
      gload_lds16(Bt + (size_t)grb * 256 + cs, &lds[1][rb][0]);
    }
  }
  __syncthreads();
  int wm = w >> 1, wn = w & 1;
  int g = l >> 4, r = l & 15;
  int rs = r & 7;
  f32x4 acc[2][2];
#pragma unroll
  for (int mi = 0; mi < 2; ++mi)
#pragma unroll
    for (int ni = 0; ni < 2; ++ni)
#pragma unroll
      for (int q = 0; q < 4; ++q) acc[mi][ni][q] = 0.f;
#pragma unroll
  for (int t = 0; t < 8; ++t) {
    int ck = ((4 * t + g) ^ rs) << 3;
    bf16x8 fa[2], fb[2];
#pragma unroll
    for (int mi = 0; mi < 2; ++mi)
      fa[mi] = *(const bf16x8*)&lds[0][wm * 32 + mi * 16 + r][ck];
#pragma unroll
    for (int ni = 0; ni < 2; ++ni)
      fb[ni] = *(const bf16x8*)&lds[1][wn * 32 + ni * 16 + r][ck];
#pragma unroll
    for (int mi = 0; mi < 2; ++mi)
#pragma unroll
      for (int ni = 0; ni < 2; ++ni)
        acc[mi][ni] = __builtin_amdgcn_mfma_f32_16x16x32_bf16(fb[ni], fa[mi], acc[mi][ni], 0, 0, 0);
  }
  if (MODE == 0) {
#pragma unroll
    for (int mi = 0; mi < 2; ++mi) {
      int gr = row0 + wm * 32 + mi * 16 + r;
      float vv[2][4];
      float mloc = -3e38f;
#pragma unroll
      for (int ni = 0; ni < 2; ++ni) {
        int gc0 = col0 + wn * 32 + ni * 16 + g * 4;
#pragma unroll
        for (int q = 0; q < 4; ++q) {
          int gc = gc0 + q;
          float v = (gc < N) ? (acc[mi][ni][q] + bias[gc]) : -3e38f;
          vv[ni][q] = v;
          mloc = fmaxf(mloc, v);
        }
      }
      float sloc = 0.f;
#pragma unroll
      for (int ni = 0; ni < 2; ++ni) {
        int gc0 = col0 + wn * 32 + ni * 16 + g * 4;
#pragma unroll
        for (int q = 0; q < 4; ++q)
          if (gc0 + q < N) sloc += expf(vv[ni][q] - mloc);
      }
      // merge across g (lanes xor 16, 32)
#pragma unroll
      for (int off = 16; off < 64; off <<= 1) {
        float mo = __shfl_xor(mloc, off);
        float so = __shfl_xor(sloc, off);
        float mn = fmaxf(mloc, mo);
        sloc = sloc * expf(mloc - mn) + so * expf(mo - mn);
        mloc = mn;
      }
      if (g == 0 && gr < M) {
        int hb = blockIdx.x * 2 + wn;
        float2* sp = (float2*)(outp + 2 * ((size_t)hb * M + gr));
        *sp = make_float2(mloc, sloc);
      }
    }
  } else {
#pragma unroll
    for (int mi = 0; mi < 2; ++mi) {
      int gr = row0 + wm * 32 + mi * 16 + r;
      if (gr >= M) continue;
      float L = lse[gr];
      float* crow = outp + (size_t)gr * N;
#pragma unroll
      for (int ni = 0; ni < 2; ++ni) {
        int gc0 = col0 + wn * 32 + ni * 16 + g * 4;
        f32x4 v = acc[mi][ni];
        if (gc0 + 4 <= N) {
          f32x4 bv = *(const f32x4*)(bias + gc0);
#pragma unroll
          for (int q = 0; q < 4; ++q) v[q] = v[q] + bv[q] - L;
          *(f32x4*)(crow + gc0) = v;
        } else {
#pragma unroll
          for (int q = 0; q < 4; ++q)
            if (gc0 + q < N) crow[gc0 + q] = v[q] + bias[gc0 + q] - L;
        }
      }
    }
  }
}

// lse[row] = online-merge of NH (m,s) partials, coalesced reads
__global__ __launch_bounds__(256) void lse_kernel(const float* __restrict__ stats,
                                                  float* __restrict__ lse, int M, int NH) {
  int row = blockIdx.x * 256 + threadIdx.x;
  if (row >= M) return;
  float m = -3e38f, s = 0.f;
  for (int hb = 0; hb < NH; ++hb) {
    float2 v = *(const float2*)(stats + 2 * ((size_t)hb * M + row));
    float mn = fmaxf(m, v.x);
    s = s * expf(m - mn) + v.y * expf(v.x - mn);
    m = mn;
  }
  lse[row] = m + logf(s);
}

extern "C" void kernel_launch(void* const* d_in, const int* in_sizes, int n_in,
                              void* d_out, int out_size, void* d_ws, size_t ws_size,
                              hipStream_t stream) {
  const int N = NND, E = NED;
  const float* x      = (const float*)d_in[0];
  const int*   ei     = (const int*)d_in[1];
  const float* pseudo = (const float*)d_in[2];
  const float* W_lin  = (const float*)d_in[3];
  const float* b_lin  = (const float*)d_in[4];
  const float* w1  = (const float*)d_in[5];
  const float* r1  = (const float*)d_in[6];
  const float* bi1 = (const float*)d_in[7];
  const float* w2  = (const float*)d_in[8];
  const float* r2  = (const float*)d_in[9];
  const float* bi2 = (const float*)d_in[10];
  const float* w3  = (const float*)d_in[11];
  const float* r3  = (const float*)d_in[12];
  const float* bi3 = (const float*)d_in[13];
  const float* W1  = (const float*)d_in[14];
  const float* b1  = (const float*)d_in[15];
  const float* W2  = (const float*)d_in[16];
  const float* b2  = (const float*)d_in[17];
  const int* erow = ei;
  const int* ecol = ei + E;

  // Scratch carved out of d_out (dead before pass C overwrites all of d_out)
  char* scratch = (char*)d_out;
  size_t off = 0;
  auto alloc = [&](size_t bytes) -> void* {
    void* p = scratch + off;
    off = (off + bytes + 255) & ~(size_t)255;
    return p;
  };
  float* Bbuf   = (float*)alloc((size_t)N * 1664 * 4);
  float* h0     = (float*)alloc((size_t)N * 16 * 4);
  float* h1     = (float*)alloc((size_t)N * 32 * 4);
  float* h2     = (float*)alloc((size_t)N * 64 * 4);
  float* h3     = (float*)alloc((size_t)N * 128 * 4);
  unsigned short* Wth = (unsigned short*)alloc((size_t)321024 * 2);
  unsigned short* Wtl = (unsigned short*)alloc((size_t)321024 * 2);
  float* Pbuf   = (float*)alloc((size_t)4 * N * 128 * 4);  // also fits 2*N*256
  float* stats  = (float*)alloc((size_t)216 * N * 2 * 4);  // (m,s) per (col-half, row)
  float* ew     = (float*)alloc((size_t)E * 4 * 4);
  int*   ek     = (int*)alloc((size_t)E * 4 * 4);
  int*   deg    = (int*)alloc((size_t)N * 4);
  float* deginv = (float*)alloc((size_t)N * 4);
  int*   rowptr = (int*)alloc((size_t)(N + 1) * 4);
  int*   cursor = (int*)alloc((size_t)N * 4);
  int*   csr    = (int*)alloc((size_t)E * 4);

  // Buffers alive during pass C go in d_ws
  unsigned short* h4b = (unsigned short*)d_ws;                                 // N*256 bf16
  unsigned short* W2t = (unsigned short*)((char*)d_ws + (size_t)N * 256 * 2);  // N*256 bf16
  float* lse = (float*)((char*)d_ws + (size_t)N * 256 * 4);                    // N f32

  // ---- graph prep ----
  zero_int_kernel<<<(N + 255) / 256, 256, 0, stream>>>(deg, N);
  edge_prep_kernel<<<(E + 255) / 256, 256, 0, stream>>>(erow, pseudo, ew, ek, deg, E);
  scan_kernel<<<1, 1024, 0, stream>>>(deg, rowptr, cursor, deginv, N);
  csr_fill_kernel<<<(E + 255) / 256, 256, 0, stream>>>(erow, cursor, csr, E);

  // ---- all weight splits in one launch ----
  weights_prep_kernel<<<323, 256, 0, stream>>>(W_lin, w1, r1, w2, r2, w3, r3, W1, Wth, Wtl);

  auto cgrid = [](int M_, int F_) { return dim3((M_ * (F_ / 4) + 255) / 256); };

  // ---- stage 0: h0 = elu(x @ W_lin + b_lin) ----
  gemm_x3_partial_kernel<16><<<dim3(1, 108, 4), 256, 0, stream>>>(x, Wth + 0, Wtl + 0, Pbuf, N, 544, 16, 4);
  combine_elu_kernel<<<cgrid(N, 16), 256, 0, stream>>>(Pbuf, b_lin, h0, nullptr, N, 16, 4);

  // ---- spline layer 1 (16 -> 32), Kd = 416 ----
  b_build_kernel<<<N, 64, 26 * 16 * 4, stream>>>(h0, ecol, ew, ek, rowptr, csr, deginv, Bbuf, 16);
  gemm_x3_partial_kernel<32><<<dim3(1, 108, 4), 256, 0, stream>>>(Bbuf, Wth + 8704, Wtl + 8704, Pbuf, N, 416, 32, 4);
  combine_elu_kernel<<<cgrid(N, 32), 256, 0, stream>>>(Pbuf, bi1, h1, nullptr, N, 32, 4);

  // ---- spline layer 2 (32 -> 64), Kd = 832 ----
  b_build_kernel<<<N, 128, 26 * 32 * 4, stream>>>(h1, ecol, ew, ek, rowptr, csr, deginv, Bbuf, 32);
  gemm_x3_partial_kernel<64><<<dim3(1, 108, 4), 256, 0, stream>>>(Bbuf, Wth + 22016, Wtl + 22016, Pbuf, N, 832, 64, 4);
  combine_elu_kernel<<<cgrid(N, 64), 256, 0, stream>>>(Pbuf, bi2, h2, nullptr, N, 64, 4);

  // ---- spline layer 3 (64 -> 128), Kd = 1664 ----
  b_build_kernel<<<N, 256, 26 * 64 * 4, stream>>>(h2, ecol, ew, ek, rowptr, csr, deginv, Bbuf, 64);
  gemm_x3_partial_kernel<128><<<dim3(1, 108, 4), 256, 0, stream>>>(Bbuf, Wth + 75264, Wtl + 75264, Pbuf, N, 1664, 128, 4);
  combine_elu_kernel<<<cgrid(N, 128), 256, 0, stream>>>(Pbuf, bi3, h3, nullptr, N, 128, 4);

  // ---- stage 4: h4 = elu(h3 @ W1 + b1) -> bf16 ----
  gemm_x3_partial_kernel<128><<<dim3(2, 108, 2), 256, 0, stream>>>(h3, Wth + 288256, Wtl + 288256, Pbuf, N, 128, 256, 2);
  combine_elu_kernel<<<cgrid(N, 256), 256, 0, stream>>>(Pbuf, b1, nullptr, h4b, N, 256, 2);

  // ---- W2 -> bf16 transposed ----
  w2_cast_transpose_kernel<<<dim3(216, 8), dim3(32, 8), 0, stream>>>(W2, W2t, 256, N);

  // ---- pass A: softmax partials (no logits write) ----
  gemm_final_kernel<0><<<dim3(108, 108), 256, 0, stream>>>(h4b, W2t, b2, nullptr, stats, N, N);

  // ---- pass B: lse per row ----
  lse_kernel<<<(N + 255) / 256, 256, 0, stream>>>(stats, lse, N, 216);

  // ---- pass C: recompute logits, write logit - lse ----
  gemm_final_kernel<1><<<dim3(108, 108), 256, 0, stream>>>(h4b, W2t, b2, lse, (float*)d_out, N, N);

  (void)in_sizes; (void)n_in; (void)out_size; (void)ws_size;
}

// Round 5
// 392.400 us; speedup vs baseline: 1.2556x; 1.2556x over previous
//
#include <hip/hip_runtime.h>
#include <hip/hip_bf16.h>

#define NND 6890
#define NED 41340

typedef __bf16 bf16x8 __attribute__((ext_vector_type(8)));
typedef float f32x4 __attribute__((ext_vector_type(4)));
typedef unsigned short u16x4 __attribute__((ext_vector_type(4)));
typedef unsigned short u16x8 __attribute__((ext_vector_type(8)));

__device__ inline unsigned short f32_bf16(float f) {
  unsigned int u = __float_as_uint(f);
  unsigned int r = (u + 0x7FFFu + ((u >> 16) & 1u)) >> 16;
  return (unsigned short)r;
}
__device__ inline void split2(float v, unsigned short& hi, unsigned short& lo) {
  unsigned short h = f32_bf16(v);
  float hf = __uint_as_float((unsigned int)h << 16);
  hi = h;
  lo = f32_bf16(v - hf);
}
__device__ inline float elu_f(float v) { return v > 0.f ? v : (expf(v) - 1.f); }

__device__ __forceinline__ void gload_lds16(const void* g, void* l) {
  __builtin_amdgcn_global_load_lds((const __attribute__((address_space(1))) void*)g,
                                   (__attribute__((address_space(3))) void*)l, 16, 0, 0);
}

__global__ void zero_int_kernel(int* p, int n) {
  int i = blockIdx.x * blockDim.x + threadIdx.x;
  if (i < n) p[i] = 0;
}

__global__ void edge_prep_kernel(const int* __restrict__ erow, const float* __restrict__ pseudo,
                                 float* __restrict__ ew, int* __restrict__ ek,
                                 int* __restrict__ deg, int E) {
  int e = blockIdx.x * blockDim.x + threadIdx.x;
  if (e >= E) return;
  float p0 = pseudo[2 * e + 0] * 4.0f;
  float p1 = pseudo[2 * e + 1] * 4.0f;
  int i0 = (int)floorf(p0); i0 = i0 < 0 ? 0 : (i0 > 3 ? 3 : i0);
  int i1 = (int)floorf(p1); i1 = i1 < 0 ? 0 : (i1 > 3 ? 3 : i1);
  float f0 = p0 - (float)i0, f1 = p1 - (float)i1;
  ew[4 * e + 0] = (1.f - f0) * (1.f - f1);
  ew[4 * e + 1] = f0 * (1.f - f1);
  ew[4 * e + 2] = (1.f - f0) * f1;
  ew[4 * e + 3] = f0 * f1;
  int b = i0 + 5 * i1;
  ek[4 * e + 0] = b; ek[4 * e + 1] = b + 1; ek[4 * e + 2] = b + 5; ek[4 * e + 3] = b + 6;
  atomicAdd(&deg[erow[e]], 1);
}

__global__ void scan_kernel(const int* __restrict__ deg, int* __restrict__ rowptr,
                            int* __restrict__ cursor, float* __restrict__ deginv, int n) {
  __shared__ int part[1024];
  int t = threadIdx.x;
  int CH = (n + 1023) >> 10;
  int base = t * CH;
  int s = 0;
  for (int j = 0; j < CH; ++j) { int i = base + j; if (i < n) s += deg[i]; }
  part[t] = s;
  __syncthreads();
  for (int off = 1; off < 1024; off <<= 1) {
    int v = (t >= off) ? part[t - off] : 0;
    __syncthreads();
    part[t] += v;
    __syncthreads();
  }
  int run = (t == 0) ? 0 : part[t - 1];
  for (int j = 0; j < CH; ++j) {
    int i = base + j;
    if (i < n) {
      rowptr[i] = run; cursor[i] = run;
      int d = deg[i];
      deginv[i] = 1.0f / fmaxf((float)d, 1.0f);
      run += d;
    }
  }
  if (t == 1023) rowptr[n] = part[1023];
}

__global__ void csr_fill_kernel(const int* __restrict__ erow, int* __restrict__ cursor,
                                int* __restrict__ csr, int E) {
  int e = blockIdx.x * blockDim.x + threadIdx.x;
  if (e >= E) return;
  int slot = atomicAdd(&cursor[erow[e]], 1);
  csr[slot] = e;
}

// B[r, k*Fin+i] = deginv[r] * sum_{edges into r} w[e,s(k)] * x[col[e], i]; last Fin cols = x[r]
__global__ void b_build_kernel(const float* __restrict__ x, const int* __restrict__ ecol,
                               const float* __restrict__ ew, const int* __restrict__ ek,
                               const int* __restrict__ rowptr, const int* __restrict__ csr,
                               const float* __restrict__ deginv,
                               float* __restrict__ B, int Fin) {
  extern __shared__ float lds[];  // 26*Fin floats
  int r = blockIdx.x;
  int T = blockDim.x;  // 4*Fin
  int tid = threadIdx.x;
  int nb = 25 * Fin;
  for (int j = tid; j < nb; j += T) lds[j] = 0.f;
  if (tid < Fin) lds[nb + tid] = x[(size_t)r * Fin + tid];
  __syncthreads();
  int p0 = rowptr[r], p1 = rowptr[r + 1];
  int s = tid / Fin;
  int i = tid - s * Fin;
  for (int p = p0; p < p1; ++p) {
    int e = csr[p];
    int c = ecol[e];
    float wv = ew[4 * e + s];
    int k = ek[4 * e + s];
    float xv = x[(size_t)c * Fin + i];
    atomicAdd(&lds[k * Fin + i], wv * xv);
  }
  __syncthreads();
  float dinv = deginv[r];
  int tot = nb + Fin;
  for (int j = tid; j < tot; j += T) {
    float v = lds[j];
    if (j < nb) v *= dinv;
    B[(size_t)r * tot + j] = v;
  }
}

// All weight splits (hi/lo bf16, transposed to [F, ldt]) in one kernel.
__global__ void weights_prep_kernel(const float* __restrict__ W_lin, const float* __restrict__ w1,
                                    const float* __restrict__ r1, const float* __restrict__ w2,
                                    const float* __restrict__ r2, const float* __restrict__ w3,
                                    const float* __restrict__ r3, const float* __restrict__ W1,
                                    unsigned short* __restrict__ Th, unsigned short* __restrict__ Tl) {
  const int tstart[9] = {0, 17, 30, 31, 81, 83, 283, 291, 323};
  const int jK[8]    = {544, 400, 16, 800, 32, 1600, 64, 128};
  const int jF[8]    = {16, 32, 32, 64, 64, 128, 128, 256};
  const int jldt[8]  = {544, 416, 416, 832, 832, 1664, 1664, 128};
  const int jkoff[8] = {0, 0, 400, 0, 800, 0, 1600, 0};
  const int jdst[8]  = {0, 8704, 8704, 22016, 22016, 75264, 75264, 288256};
  int b = blockIdx.x;
  int job = 0;
  while (job < 7 && b >= tstart[job + 1]) ++job;
  int t = b - tstart[job];
  int fxc = (jF[job] + 31) >> 5;
  int kt = t / fxc, ft = t % fxc;
  const float* src;
  switch (job) {
    case 0: src = W_lin; break;
    case 1: src = w1; break;
    case 2: src = r1; break;
    case 3: src = w2; break;
    case 4: src = r2; break;
    case 5: src = w3; break;
    case 6: src = r3; break;
    default: src = W1; break;
  }
  int K = jK[job], F = jF[job], ldt = jldt[job], koff = jkoff[job];
  unsigned short* th = Th + jdst[job];
  unsigned short* tl = Tl + jdst[job];
  int k0 = kt * 32, c0 = ft * 32;
  __shared__ float tbuf[32][33];
  int tx = threadIdx.x & 31, ty = threadIdx.x >> 5;  // 32 x 8
  for (int j = ty; j < 32; j += 8) {
    int gk = k0 + j, gc = c0 + tx;
    tbuf[j][tx] = (gk < K && gc < F) ? src[(size_t)gk * F + gc] : 0.f;
  }
  __syncthreads();
  for (int j = ty; j < 32; j += 8) {
    int gc = c0 + j, gk = k0 + tx;
    if (gc < F && gk < K) {
      unsigned short h, lo2;
      split2(tbuf[tx][j], h, lo2);
      th[(size_t)gc * ldt + koff + gk] = h;
      tl[(size_t)gc * ldt + koff + gk] = lo2;
    }
  }
}

// Partial GEMM (bf16x3 split) over K-slice z: P[z][M][F] = A @ W (no bias/elu).
template <int BN>
__global__ __launch_bounds__(256) void gemm_x3_partial_kernel(
    const float* __restrict__ A, const unsigned short* __restrict__ Wth,
    const unsigned short* __restrict__ Wtl, float* __restrict__ P,
    int M, int Kd, int F, int KS) {
  constexpr int BK = 32;
  constexpr int NF = BN / 16;
  constexpr int WU = (BK * BN) / 4;
  constexpr int WREP = (WU + 255) / 256;
  __shared__ __align__(16) unsigned short Ah[2][64][40];
  __shared__ __align__(16) unsigned short Al[2][64][40];
  __shared__ __align__(16) unsigned short Wh[2][BN][40];
  __shared__ __align__(16) unsigned short Wl[2][BN][40];
  int tid = threadIdx.x;
  int wave = tid >> 6, lane = tid & 63;
  int g = lane >> 4, r = lane & 15;
  int row0 = blockIdx.y * 64;
  int col0 = blockIdx.x * BN;
  int z = blockIdx.z;
  int nt = Kd >> 5;
  int ta = z * nt / KS, tb = (z + 1) * nt / KS;

  f32x4 acc[NF];
#pragma unroll
  for (int n = 0; n < NF; ++n)
#pragma unroll
    for (int q = 0; q < 4; ++q) acc[n][q] = 0.f;

  f32x4 ra[2];
  u16x4 rwh[WREP], rwl[WREP];

  auto loadTiles = [&](int kb) {
#pragma unroll
    for (int rep = 0; rep < 2; ++rep) {
      int u = tid + rep * 256;
      int rr = u >> 3, kq = (u & 7) * 4;
      int gr = row0 + rr;
      f32x4 v = {0.f, 0.f, 0.f, 0.f};
      if (gr < M) v = *(const f32x4*)(A + (size_t)gr * Kd + kb + kq);
      ra[rep] = v;
    }
#pragma unroll
    for (int rep = 0; rep < WREP; ++rep) {
      int u = tid + rep * 256;
      if (u < WU) {
        int cc = u >> 3, kq = (u & 7) * 4;
        rwh[rep] = *(const u16x4*)(Wth + (size_t)(col0 + cc) * Kd + kb + kq);
        rwl[rep] = *(const u16x4*)(Wtl + (size_t)(col0 + cc) * Kd + kb + kq);
      }
    }
  };
  auto writeLDS = [&](int buf) {
#pragma unroll
    for (int rep = 0; rep < 2; ++rep) {
      int u = tid + rep * 256;
      int rr = u >> 3, kq = (u & 7) * 4;
      u16x4 h, l;
#pragma unroll
      for (int j = 0; j < 4; ++j) {
        unsigned short hh, ll;
        split2(ra[rep][j], hh, ll);
        h[j] = hh; l[j] = ll;
      }
      *(u16x4*)&Ah[buf][rr][kq] = h;
      *(u16x4*)&Al[buf][rr][kq] = l;
    }
#pragma unroll
    for (int rep = 0; rep < WREP; ++rep) {
      int u = tid + rep * 256;
      if (u < WU) {
        int cc = u >> 3, kq = (u & 7) * 4;
        *(u16x4*)&Wh[buf][cc][kq] = rwh[rep];
        *(u16x4*)&Wl[buf][cc][kq] = rwl[rep];
      }
    }
  };

  int n = tb - ta;
  loadTiles(ta * BK);
  writeLDS(0);
  __syncthreads();
  for (int tt = 0; tt < n; ++tt) {
    int cur = tt & 1;
    if (tt + 1 < n) loadTiles((ta + tt + 1) * BK);
    bf16x8 fah = *(const bf16x8*)&Ah[cur][wave * 16 + r][g * 8];
    bf16x8 fal = *(const bf16x8*)&Al[cur][wave * 16 + r][g * 8];
#pragma unroll
    for (int nn = 0; nn < NF; ++nn) {
      bf16x8 fbh = *(const bf16x8*)&Wh[cur][nn * 16 + r][g * 8];
      bf16x8 fbl = *(const bf16x8*)&Wl[cur][nn * 16 + r][g * 8];
      acc[nn] = __builtin_amdgcn_mfma_f32_16x16x32_bf16(fah, fbh, acc[nn], 0, 0, 0);
      acc[nn] = __builtin_amdgcn_mfma_f32_16x16x32_bf16(fal, fbh, acc[nn], 0, 0, 0);
      acc[nn] = __builtin_amdgcn_mfma_f32_16x16x32_bf16(fah, fbl, acc[nn], 0, 0, 0);
    }
    if (tt + 1 < n) writeLDS(cur ^ 1);
    __syncthreads();
  }
#pragma unroll
  for (int nn = 0; nn < NF; ++nn) {
    int gc = col0 + nn * 16 + r;
#pragma unroll
    for (int q = 0; q < 4; ++q) {
      int gr = row0 + wave * 16 + g * 4 + q;
      if (gr < M) P[((size_t)z * M + gr) * F + gc] = acc[nn][q];
    }
  }
}

// out = elu(sum_z P[z] + bias); f32 or bf16 out
__global__ __launch_bounds__(256) void combine_elu_kernel(
    const float* __restrict__ P, const float* __restrict__ bias,
    float* __restrict__ outF, unsigned short* __restrict__ outB,
    int M, int F, int KS) {
  int i4 = blockIdx.x * 256 + threadIdx.x;
  int fv = F >> 2;
  int total = M * fv;
  if (i4 >= total) return;
  int gr = i4 / fv, c4 = (i4 - gr * fv) * 4;
  f32x4 s = {0.f, 0.f, 0.f, 0.f};
  for (int z = 0; z < KS; ++z)
    s += *(const f32x4*)(P + ((size_t)z * M + gr) * F + c4);
  f32x4 bv = *(const f32x4*)(bias + c4);
#pragma unroll
  for (int j = 0; j < 4; ++j) s[j] = elu_f(s[j] + bv[j]);
  if (outB) {
    u16x4 o;
#pragma unroll
    for (int j = 0; j < 4; ++j) o[j] = f32_bf16(s[j]);
    *(u16x4*)(outB + (size_t)gr * F + c4) = o;
  } else {
    *(f32x4*)(outF + (size_t)gr * F + c4) = s;
  }
}

// W2 [K=256, N] f32  ->  Wt [N, K] bf16
__global__ void w2_cast_transpose_kernel(const float* __restrict__ W2,
                                         unsigned short* __restrict__ Wt, int K, int N) {
  __shared__ float t[32][33];
  int c0 = blockIdx.x * 32, k0 = blockIdx.y * 32;
  int tx = threadIdx.x, ty = threadIdx.y;  // 32 x 8
  for (int j = ty; j < 32; j += 8) {
    int gk = k0 + j, gc = c0 + tx;
    t[j][tx] = (gk < K && gc < N) ? W2[(size_t)gk * N + gc] : 0.f;
  }
  __syncthreads();
  for (int j = ty; j < 32; j += 8) {
    int gc = c0 + j, gk = k0 + tx;
    if (gc < N && gk < K) Wt[(size_t)gc * K + gk] = f32_bf16(t[tx][j]);
  }
}

// Final layer GEMM: 128x128 tile, BK=64 double-buffered via global_load_lds,
// superrow-rotation LDS swizzle (2-way banks, conflict-free), 4 waves x (64x64),
// swapped-operand MFMA (lane: row = base+r, cols = base+g*4+q).
// LDS tile layout: superrow = 4 rows (512B); pos(row,c) = (8*(row&3)+c+2*((row>>2)&3)) & 31.
// MODE 0: emit per-(row, 64-col wave half) online-softmax partials (m,s) -> outp(stats).
// MODE 1: write out[gr][gc] = logit + bias - lse[gr].
template <int MODE>
__global__ __launch_bounds__(256) void gemm_final_kernel(
    const unsigned short* __restrict__ A, const unsigned short* __restrict__ Bt,
    const float* __restrict__ bias, const float* __restrict__ lse,
    float* __restrict__ outp, int M, int N) {
  __shared__ __align__(16) unsigned short lds[2][2][8192];  // [buf][A/B][128*64] = 64KB
  int tid = threadIdx.x;
  int w = tid >> 6, l = tid & 63;
  int row0 = blockIdx.y * 128, col0 = blockIdx.x * 128;

  // staging decode (per-thread constants)
  int sq = l & 31;          // pos within superrow
  int shalf = l >> 5;       // which superrow of the 1KB pair

  auto STAGE = [&](int buf, int kb) {
#pragma unroll
    for (int i = 0; i < 4; ++i) {
      int sr = (w * 4 + i) * 2 + shalf;       // superrow 0..31
      int b2 = sr & 3;
      int t2 = (sq - 2 * b2) & 31;
      int a = t2 >> 3, c = t2 & 7;
      int rr = sr * 4 + a;                    // tile row 0..127
      int gra = row0 + rr; if (gra >= M) gra = M - 1;
      int grb = col0 + rr; if (grb >= N) grb = N - 1;
      gload_lds16(A + (size_t)gra * 256 + kb + c * 8, &lds[buf][0][(w * 4 + i) * 512]);
      gload_lds16(Bt + (size_t)grb * 256 + kb + c * 8, &lds[buf][1][(w * 4 + i) * 512]);
    }
  };

  int wm = w >> 1, wn = w & 1;
  int g = l >> 4, r = l & 15;
  int keyg = 8 * (r & 3) + 2 * (r >> 2) + g;  // per-lane swizzle key (+g folded)
  int aoff[4], boff[4];
#pragma unroll
  for (int f = 0; f < 4; ++f) {
    aoff[f] = (wm * 16 + f * 4 + (r >> 2)) * 256;
    boff[f] = (wn * 16 + f * 4 + (r >> 2)) * 256;
  }

  f32x4 acc[4][4];
#pragma unroll
  for (int mi = 0; mi < 4; ++mi)
#pragma unroll
    for (int ni = 0; ni < 4; ++ni)
#pragma unroll
      for (int q = 0; q < 4; ++q) acc[mi][ni][q] = 0.f;

  STAGE(0, 0);
  __syncthreads();
#pragma unroll
  for (int ks = 0; ks < 4; ++ks) {
    int buf = ks & 1;
    if (ks < 3) STAGE(buf ^ 1, (ks + 1) * 64);
#pragma unroll
    for (int sub = 0; sub < 2; ++sub) {
      int pc = ((keyg + 4 * sub) & 31) * 8;
      bf16x8 fa[4], fb[4];
#pragma unroll
      for (int mi = 0; mi < 4; ++mi) fa[mi] = *(const bf16x8*)&lds[buf][0][aoff[mi] + pc];
#pragma unroll
      for (int ni = 0; ni < 4; ++ni) fb[ni] = *(const bf16x8*)&lds[buf][1][boff[ni] + pc];
#pragma unroll
      for (int mi = 0; mi < 4; ++mi)
#pragma unroll
        for (int ni = 0; ni < 4; ++ni)
          acc[mi][ni] = __builtin_amdgcn_mfma_f32_16x16x32_bf16(fb[ni], fa[mi], acc[mi][ni], 0, 0, 0);
    }
    __syncthreads();
  }

  if (MODE == 0) {
    // bias for this lane's 16 columns (independent of row-frag)
    float bb[4][4];
#pragma unroll
    for (int ni = 0; ni < 4; ++ni) {
      int gc0 = col0 + wn * 64 + ni * 16 + g * 4;
#pragma unroll
      for (int q = 0; q < 4; ++q)
        bb[ni][q] = (gc0 + q < N) ? bias[gc0 + q] : 0.f;
    }
#pragma unroll
    for (int mi = 0; mi < 4; ++mi) {
      int gr = row0 + wm * 64 + mi * 16 + r;
      float vv[4][4];
      float mloc = -3e38f;
#pragma unroll
      for (int ni = 0; ni < 4; ++ni) {
        int gc0 = col0 + wn * 64 + ni * 16 + g * 4;
#pragma unroll
        for (int q = 0; q < 4; ++q) {
          float v = (gc0 + q < N) ? (acc[mi][ni][q] + bb[ni][q]) : -3e38f;
          vv[ni][q] = v;
          mloc = fmaxf(mloc, v);
        }
      }
      float sloc = 0.f;
#pragma unroll
      for (int ni = 0; ni < 4; ++ni) {
        int gc0 = col0 + wn * 64 + ni * 16 + g * 4;
#pragma unroll
        for (int q = 0; q < 4; ++q)
          if (gc0 + q < N) sloc += __expf(vv[ni][q] - mloc);
      }
#pragma unroll
      for (int off = 16; off < 64; off <<= 1) {
        float mo = __shfl_xor(mloc, off);
        float so = __shfl_xor(sloc, off);
        float mn = fmaxf(mloc, mo);
        sloc = sloc * __expf(mloc - mn) + so * __expf(mo - mn);
        mloc = mn;
      }
      if (g == 0 && gr < M) {
        int hb = blockIdx.x * 2 + wn;
        *(float2*)(outp + 2 * ((size_t)hb * M + gr)) = make_float2(mloc, sloc);
      }
    }
  } else {
#pragma unroll
    for (int mi = 0; mi < 4; ++mi) {
      int gr = row0 + wm * 64 + mi * 16 + r;
      if (gr >= M) continue;
      float L = lse[gr];
      float* crow = outp + (size_t)gr * N;
#pragma unroll
      for (int ni = 0; ni < 4; ++ni) {
        int gc0 = col0 + wn * 64 + ni * 16 + g * 4;
        f32x4 v = acc[mi][ni];
        if (gc0 + 4 <= N) {
          f32x4 bv = *(const f32x4*)(bias + gc0);
#pragma unroll
          for (int q = 0; q < 4; ++q) v[q] = v[q] + bv[q] - L;
          *(f32x4*)(crow + gc0) = v;
        } else {
#pragma unroll
          for (int q = 0; q < 4; ++q)
            if (gc0 + q < N) crow[gc0 + q] = v[q] + bias[gc0 + q] - L;
        }
      }
    }
  }
}

// lse[row] = online-merge of NH (m,s) partials
__global__ __launch_bounds__(256) void lse_kernel(const float* __restrict__ stats,
                                                  float* __restrict__ lse, int M, int NH) {
  int row = blockIdx.x * 256 + threadIdx.x;
  if (row >= M) return;
  float m = -3e38f, s = 0.f;
  for (int hb = 0; hb < NH; ++hb) {
    float2 v = *(const float2*)(stats + 2 * ((size_t)hb * M + row));
    float mn = fmaxf(m, v.x);
    s = s * __expf(m - mn) + v.y * __expf(v.x - mn);
    m = mn;
  }
  lse[row] = m + logf(s);
}

extern "C" void kernel_launch(void* const* d_in, const int* in_sizes, int n_in,
                              void* d_out, int out_size, void* d_ws, size_t ws_size,
                              hipStream_t stream) {
  const int N = NND, E = NED;
  const float* x      = (const float*)d_in[0];
  const int*   ei     = (const int*)d_in[1];
  const float* pseudo = (const float*)d_in[2];
  const float* W_lin  = (const float*)d_in[3];
  const float* b_lin  = (const float*)d_in[4];
  const float* w1  = (const float*)d_in[5];
  const float* r1  = (const float*)d_in[6];
  const float* bi1 = (const float*)d_in[7];
  const float* w2  = (const float*)d_in[8];
  const float* r2  = (const float*)d_in[9];
  const float* bi2 = (const float*)d_in[10];
  const float* w3  = (const float*)d_in[11];
  const float* r3  = (const float*)d_in[12];
  const float* bi3 = (const float*)d_in[13];
  const float* W1  = (const float*)d_in[14];
  const float* b1  = (const float*)d_in[15];
  const float* W2  = (const float*)d_in[16];
  const float* b2  = (const float*)d_in[17];
  const int* erow = ei;
  const int* ecol = ei + E;

  // Scratch carved out of d_out (dead before pass C overwrites all of d_out)
  char* scratch = (char*)d_out;
  size_t off = 0;
  auto alloc = [&](size_t bytes) -> void* {
    void* p = scratch + off;
    off = (off + bytes + 255) & ~(size_t)255;
    return p;
  };
  float* Bbuf   = (float*)alloc((size_t)N * 1664 * 4);
  float* h0     = (float*)alloc((size_t)N * 16 * 4);
  float* h1     = (float*)alloc((size_t)N * 32 * 4);
  float* h2     = (float*)alloc((size_t)N * 64 * 4);
  float* h3     = (float*)alloc((size_t)N * 128 * 4);
  unsigned short* Wth = (unsigned short*)alloc((size_t)321024 * 2);
  unsigned short* Wtl = (unsigned short*)alloc((size_t)321024 * 2);
  float* Pbuf   = (float*)alloc((size_t)4 * N * 128 * 4);  // also fits 2*N*256
  float* stats  = (float*)alloc((size_t)108 * N * 2 * 4);  // (m,s) per (64-col half, row)
  float* ew     = (float*)alloc((size_t)E * 4 * 4);
  int*   ek     = (int*)alloc((size_t)E * 4 * 4);
  int*   deg    = (int*)alloc((size_t)N * 4);
  float* deginv = (float*)alloc((size_t)N * 4);
  int*   rowptr = (int*)alloc((size_t)(N + 1) * 4);
  int*   cursor = (int*)alloc((size_t)N * 4);
  int*   csr    = (int*)alloc((size_t)E * 4);

  // Buffers alive during pass C go in d_ws
  unsigned short* h4b = (unsigned short*)d_ws;                                 // N*256 bf16
  unsigned short* W2t = (unsigned short*)((char*)d_ws + (size_t)N * 256 * 2);  // N*256 bf16
  float* lse = (float*)((char*)d_ws + (size_t)N * 256 * 4);                    // N f32

  // ---- graph prep ----
  zero_int_kernel<<<(N + 255) / 256, 256, 0, stream>>>(deg, N);
  edge_prep_kernel<<<(E + 255) / 256, 256, 0, stream>>>(erow, pseudo, ew, ek, deg, E);
  scan_kernel<<<1, 1024, 0, stream>>>(deg, rowptr, cursor, deginv, N);
  csr_fill_kernel<<<(E + 255) / 256, 256, 0, stream>>>(erow, cursor, csr, E);

  // ---- all weight splits in one launch ----
  weights_prep_kernel<<<323, 256, 0, stream>>>(W_lin, w1, r1, w2, r2, w3, r3, W1, Wth, Wtl);

  auto cgrid = [](int M_, int F_) { return dim3((M_ * (F_ / 4) + 255) / 256); };

  // ---- stage 0: h0 = elu(x @ W_lin + b_lin) ----
  gemm_x3_partial_kernel<16><<<dim3(1, 108, 4), 256, 0, stream>>>(x, Wth + 0, Wtl + 0, Pbuf, N, 544, 16, 4);
  combine_elu_kernel<<<cgrid(N, 16), 256, 0, stream>>>(Pbuf, b_lin, h0, nullptr, N, 16, 4);

  // ---- spline layer 1 (16 -> 32), Kd = 416 ----
  b_build_kernel<<<N, 64, 26 * 16 * 4, stream>>>(h0, ecol, ew, ek, rowptr, csr, deginv, Bbuf, 16);
  gemm_x3_partial_kernel<32><<<dim3(1, 108, 4), 256, 0, stream>>>(Bbuf, Wth + 8704, Wtl + 8704, Pbuf, N, 416, 32, 4);
  combine_elu_kernel<<<cgrid(N, 32), 256, 0, stream>>>(Pbuf, bi1, h1, nullptr, N, 32, 4);

  // ---- spline layer 2 (32 -> 64), Kd = 832 ----
  b_build_kernel<<<N, 128, 26 * 32 * 4, stream>>>(h1, ecol, ew, ek, rowptr, csr, deginv, Bbuf, 32);
  gemm_x3_partial_kernel<64><<<dim3(1, 108, 4), 256, 0, stream>>>(Bbuf, Wth + 22016, Wtl + 22016, Pbuf, N, 832, 64, 4);
  combine_elu_kernel<<<cgrid(N, 64), 256, 0, stream>>>(Pbuf, bi2, h2, nullptr, N, 64, 4);

  // ---- spline layer 3 (64 -> 128), Kd = 1664 ----
  b_build_kernel<<<N, 256, 26 * 64 * 4, stream>>>(h2, ecol, ew, ek, rowptr, csr, deginv, Bbuf, 64);
  gemm_x3_partial_kernel<128><<<dim3(1, 108, 4), 256, 0, stream>>>(Bbuf, Wth + 75264, Wtl + 75264, Pbuf, N, 1664, 128, 4);
  combine_elu_kernel<<<cgrid(N, 128), 256, 0, stream>>>(Pbuf, bi3, h3, nullptr, N, 128, 4);

  // ---- stage 4: h4 = elu(h3 @ W1 + b1) -> bf16 ----
  gemm_x3_partial_kernel<128><<<dim3(2, 108, 2), 256, 0, stream>>>(h3, Wth + 288256, Wtl + 288256, Pbuf, N, 128, 256, 2);
  combine_elu_kernel<<<cgrid(N, 256), 256, 0, stream>>>(Pbuf, b1, nullptr, h4b, N, 256, 2);

  // ---- W2 -> bf16 transposed ----
  w2_cast_transpose_kernel<<<dim3(216, 8), dim3(32, 8), 0, stream>>>(W2, W2t, 256, N);

  // ---- pass A: softmax partials (no logits write) ----
  gemm_final_kernel<0><<<dim3(54, 54), 256, 0, stream>>>(h4b, W2t, b2, nullptr, stats, N, N);

  // ---- pass B: lse per row ----
  lse_kernel<<<(N + 255) / 256, 256, 0, stream>>>(stats, lse, N, 108);

  // ---- pass C: recompute logits, write logit - lse ----
  gemm_final_kernel<1><<<dim3(54, 54), 256, 0, stream>>>(h4b, W2t, b2, lse, (float*)d_out, N, N);

  (void)in_sizes; (void)n_in; (void)out_size; (void)ws_size;
}

// Round 6
// 384.428 us; speedup vs baseline: 1.2817x; 1.0207x over previous
//
#include <hip/hip_runtime.h>
#include <hip/hip_bf16.h>

#define NND 6890
#define NED 41340

typedef __bf16 bf16x8 __attribute__((ext_vector_type(8)));
typedef float f32x4 __attribute__((ext_vector_type(4)));
typedef unsigned short u16x4 __attribute__((ext_vector_type(4)));

__device__ inline unsigned short f32_bf16(float f) {
  unsigned int u = __float_as_uint(f);
  unsigned int r = (u + 0x7FFFu + ((u >> 16) & 1u)) >> 16;
  return (unsigned short)r;
}
__device__ inline void split2(float v, unsigned short& hi, unsigned short& lo) {
  unsigned short h = f32_bf16(v);
  float hf = __uint_as_float((unsigned int)h << 16);
  hi = h;
  lo = f32_bf16(v - hf);
}
__device__ inline float elu_f(float v) { return v > 0.f ? v : (expf(v) - 1.f); }

__device__ __forceinline__ void gload_lds16(const void* g, void* l) {
  __builtin_amdgcn_global_load_lds((const __attribute__((address_space(1))) void*)g,
                                   (__attribute__((address_space(3))) void*)l, 16, 0, 0);
}

__global__ void zero_int_kernel(int* p, int n) {
  int i = blockIdx.x * blockDim.x + threadIdx.x;
  if (i < n) p[i] = 0;
}

__global__ void edge_prep_kernel(const int* __restrict__ erow, const float* __restrict__ pseudo,
                                 float* __restrict__ ew, int* __restrict__ ek,
                                 int* __restrict__ deg, int E) {
  int e = blockIdx.x * blockDim.x + threadIdx.x;
  if (e >= E) return;
  float p0 = pseudo[2 * e + 0] * 4.0f;
  float p1 = pseudo[2 * e + 1] * 4.0f;
  int i0 = (int)floorf(p0); i0 = i0 < 0 ? 0 : (i0 > 3 ? 3 : i0);
  int i1 = (int)floorf(p1); i1 = i1 < 0 ? 0 : (i1 > 3 ? 3 : i1);
  float f0 = p0 - (float)i0, f1 = p1 - (float)i1;
  ew[4 * e + 0] = (1.f - f0) * (1.f - f1);
  ew[4 * e + 1] = f0 * (1.f - f1);
  ew[4 * e + 2] = (1.f - f0) * f1;
  ew[4 * e + 3] = f0 * f1;
  int b = i0 + 5 * i1;
  ek[4 * e + 0] = b; ek[4 * e + 1] = b + 1; ek[4 * e + 2] = b + 5; ek[4 * e + 3] = b + 6;
  atomicAdd(&deg[erow[e]], 1);
}

__global__ void scan_kernel(const int* __restrict__ deg, int* __restrict__ rowptr,
                            int* __restrict__ cursor, float* __restrict__ deginv, int n) {
  __shared__ int part[1024];
  int t = threadIdx.x;
  int CH = (n + 1023) >> 10;
  int base = t * CH;
  int s = 0;
  for (int j = 0; j < CH; ++j) { int i = base + j; if (i < n) s += deg[i]; }
  part[t] = s;
  __syncthreads();
  for (int off = 1; off < 1024; off <<= 1) {
    int v = (t >= off) ? part[t - off] : 0;
    __syncthreads();
    part[t] += v;
    __syncthreads();
  }
  int run = (t == 0) ? 0 : part[t - 1];
  for (int j = 0; j < CH; ++j) {
    int i = base + j;
    if (i < n) {
      rowptr[i] = run; cursor[i] = run;
      int d = deg[i];
      deginv[i] = 1.0f / fmaxf((float)d, 1.0f);
      run += d;
    }
  }
  if (t == 1023) rowptr[n] = part[1023];
}

__global__ void csr_fill_kernel(const int* __restrict__ erow, int* __restrict__ cursor,
                                int* __restrict__ csr, int E) {
  int e = blockIdx.x * blockDim.x + threadIdx.x;
  if (e >= E) return;
  int slot = atomicAdd(&cursor[erow[e]], 1);
  csr[slot] = e;
}

// src f32 [n4*4] -> hi/lo bf16 planes
__global__ void split_kernel(const float* __restrict__ src, unsigned short* __restrict__ oh,
                             unsigned short* __restrict__ ol, int n4) {
  int i = blockIdx.x * 256 + threadIdx.x;
  if (i >= n4) return;
  f32x4 v = *(const f32x4*)(src + 4 * i);
  u16x4 h, l;
#pragma unroll
  for (int j = 0; j < 4; ++j) {
    unsigned short hh, ll;
    split2(v[j], hh, ll);
    h[j] = hh; l[j] = ll;
  }
  *(u16x4*)(oh + 4 * i) = h;
  *(u16x4*)(ol + 4 * i) = l;
}

// B[r, k*Fin+i] accumulation in LDS (atomics), then split -> Bh/Bl bf16 planes [N][Kd=26*Fin]
__global__ void b_build_kernel(const float* __restrict__ x, const int* __restrict__ ecol,
                               const float* __restrict__ ew, const int* __restrict__ ek,
                               const int* __restrict__ rowptr, const int* __restrict__ csr,
                               const float* __restrict__ deginv,
                               unsigned short* __restrict__ Bh, unsigned short* __restrict__ Bl,
                               int Fin) {
  extern __shared__ float lds[];  // 26*Fin floats
  int r = blockIdx.x;
  int T = blockDim.x;  // 4*Fin
  int tid = threadIdx.x;
  int nb = 25 * Fin;
  for (int j = tid; j < nb; j += T) lds[j] = 0.f;
  if (tid < Fin) lds[nb + tid] = x[(size_t)r * Fin + tid];
  __syncthreads();
  int p0 = rowptr[r], p1 = rowptr[r + 1];
  int s = tid / Fin;
  int i = tid - s * Fin;
  for (int p = p0; p < p1; ++p) {
    int e = csr[p];
    int c = ecol[e];
    float wv = ew[4 * e + s];
    int k = ek[4 * e + s];
    float xv = x[(size_t)c * Fin + i];
    atomicAdd(&lds[k * Fin + i], wv * xv);
  }
  __syncthreads();
  float dinv = deginv[r];
  int tot = nb + Fin;  // = 26*Fin = Kd
  for (int j = tid; j < tot; j += T) {
    float v = lds[j];
    if (j < nb) v *= dinv;
    unsigned short h, l;
    split2(v, h, l);
    Bh[(size_t)r * tot + j] = h;
    Bl[(size_t)r * tot + j] = l;
  }
}

// All weight splits (hi/lo bf16, transposed to [F, ldt]) in one kernel.
__global__ void weights_prep_kernel(const float* __restrict__ W_lin, const float* __restrict__ w1,
                                    const float* __restrict__ r1, const float* __restrict__ w2,
                                    const float* __restrict__ r2, const float* __restrict__ w3,
                                    const float* __restrict__ r3, const float* __restrict__ W1,
                                    unsigned short* __restrict__ Th, unsigned short* __restrict__ Tl) {
  const int tstart[9] = {0, 17, 30, 31, 81, 83, 283, 291, 323};
  const int jK[8]    = {544, 400, 16, 800, 32, 1600, 64, 128};
  const int jF[8]    = {16, 32, 32, 64, 64, 128, 128, 256};
  const int jldt[8]  = {544, 416, 416, 832, 832, 1664, 1664, 128};
  const int jkoff[8] = {0, 0, 400, 0, 800, 0, 1600, 0};
  const int jdst[8]  = {0, 8704, 8704, 22016, 22016, 75264, 75264, 288256};
  int b = blockIdx.x;
  int job = 0;
  while (job < 7 && b >= tstart[job + 1]) ++job;
  int t = b - tstart[job];
  int fxc = (jF[job] + 31) >> 5;
  int kt = t / fxc, ft = t % fxc;
  const float* src;
  switch (job) {
    case 0: src = W_lin; break;
    case 1: src = w1; break;
    case 2: src = r1; break;
    case 3: src = w2; break;
    case 4: src = r2; break;
    case 5: src = w3; break;
    case 6: src = r3; break;
    default: src = W1; break;
  }
  int K = jK[job], F = jF[job], ldt = jldt[job], koff = jkoff[job];
  unsigned short* th = Th + jdst[job];
  unsigned short* tl = Tl + jdst[job];
  int k0 = kt * 32, c0 = ft * 32;
  __shared__ float tbuf[32][33];
  int tx = threadIdx.x & 31, ty = threadIdx.x >> 5;  // 32 x 8
  for (int j = ty; j < 32; j += 8) {
    int gk = k0 + j, gc = c0 + tx;
    tbuf[j][tx] = (gk < K && gc < F) ? src[(size_t)gk * F + gc] : 0.f;
  }
  __syncthreads();
  for (int j = ty; j < 32; j += 8) {
    int gc = c0 + j, gk = k0 + tx;
    if (gc < F && gk < K) {
      unsigned short h, lo2;
      split2(tbuf[tx][j], h, lo2);
      th[(size_t)gc * ldt + koff + gk] = h;
      tl[(size_t)gc * ldt + koff + gk] = lo2;
    }
  }
}

// Partial GEMM (bf16x3) over K-slice z: P[z][M][F] = A @ W.
// A, W pre-split bf16 planes; all staging via global_load_lds with per-row
// 4-chunk rotation (2-way banks = free). 64-row A tile, BN-col W tile, BK=32.
template <int BN>
__global__ __launch_bounds__(256) void gemm_x3_partial_kernel(
    const unsigned short* __restrict__ Ah, const unsigned short* __restrict__ Al,
    const unsigned short* __restrict__ Wh, const unsigned short* __restrict__ Wl,
    float* __restrict__ P, int M, int Kd, int F, int KS) {
  constexpr int AE = 64 * 32;   // elements per A plane tile
  constexpr int WE = BN * 32;
  __shared__ __align__(16) unsigned short lds[2][2 * AE + 2 * WE];
  int tid = threadIdx.x;
  int wave = tid >> 6, lane = tid & 63;
  int g = lane >> 4, r = lane & 15;
  int row0 = blockIdx.y * 64;
  int col0 = blockIdx.x * BN;
  int z = blockIdx.z;
  int nt = Kd >> 5;
  int ta = z * nt / KS, tb = (z + 1) * nt / KS;

  auto STAGE = [&](int buf, int kb) {
    {  // A tiles: 256 chunks, chunk idx = tid; row = idx>>2, pos = idx&3, src chunk = (pos-row)&3
      int rr = tid >> 2, pos = tid & 3;
      int c = (pos - rr) & 3;
      int gra = row0 + rr; if (gra >= M) gra = M - 1;
      size_t so = (size_t)gra * Kd + kb + c * 8;
      gload_lds16(Ah + so, &lds[buf][wave * 512]);
      gload_lds16(Al + so, &lds[buf][AE + wave * 512]);
    }
#pragma unroll
    for (int it = 0; it < (4 * BN + 255) / 256; ++it) {
      int idx = it * 256 + tid;
      if (idx < 4 * BN) {
        int rr = idx >> 2, pos = idx & 3;
        int c = (pos - rr) & 3;
        size_t so = (size_t)(col0 + rr) * Kd + kb + c * 8;
        gload_lds16(Wh + so, &lds[buf][2 * AE + (it * 256 + wave * 64) * 8]);
        gload_lds16(Wl + so, &lds[buf][2 * AE + WE + (it * 256 + wave * 64) * 8]);
      }
    }
  };

  constexpr int NF = BN / 16;
  f32x4 acc[NF];
#pragma unroll
  for (int n = 0; n < NF; ++n)
#pragma unroll
    for (int q = 0; q < 4; ++q) acc[n][q] = 0.f;

  int n = tb - ta;
  int rA = wave * 16 + r;
  int aoff = rA * 32 + ((g + rA) & 3) * 8;

  STAGE(0, ta * 32);
  __syncthreads();
  for (int tt = 0; tt < n; ++tt) {
    int buf = tt & 1;
    if (tt + 1 < n) STAGE(buf ^ 1, (ta + tt + 1) * 32);
    bf16x8 fah = *(const bf16x8*)&lds[buf][aoff];
    bf16x8 fal = *(const bf16x8*)&lds[buf][AE + aoff];
#pragma unroll
    for (int nn = 0; nn < NF; ++nn) {
      int rW = nn * 16 + r;
      int woff = rW * 32 + ((g + rW) & 3) * 8;
      bf16x8 fbh = *(const bf16x8*)&lds[buf][2 * AE + woff];
      bf16x8 fbl = *(const bf16x8*)&lds[buf][2 * AE + WE + woff];
      acc[nn] = __builtin_amdgcn_mfma_f32_16x16x32_bf16(fah, fbh, acc[nn], 0, 0, 0);
      acc[nn] = __builtin_amdgcn_mfma_f32_16x16x32_bf16(fal, fbh, acc[nn], 0, 0, 0);
      acc[nn] = __builtin_amdgcn_mfma_f32_16x16x32_bf16(fah, fbl, acc[nn], 0, 0, 0);
    }
    __syncthreads();
  }
#pragma unroll
  for (int nn = 0; nn < NF; ++nn) {
    int gc = col0 + nn * 16 + r;
#pragma unroll
    for (int q = 0; q < 4; ++q) {
      int gr = row0 + wave * 16 + g * 4 + q;
      if (gr < M) P[((size_t)z * M + gr) * F + gc] = acc[nn][q];
    }
  }
}

// out = elu(sum_z P[z] + bias); f32, bf16, or hi/lo-plane output
__global__ __launch_bounds__(256) void combine_elu_kernel(
    const float* __restrict__ P, const float* __restrict__ bias,
    float* __restrict__ outF, unsigned short* __restrict__ outB,
    unsigned short* __restrict__ outH, unsigned short* __restrict__ outL,
    int M, int F, int KS) {
  int i4 = blockIdx.x * 256 + threadIdx.x;
  int fv = F >> 2;
  int total = M * fv;
  if (i4 >= total) return;
  int gr = i4 / fv, c4 = (i4 - gr * fv) * 4;
  f32x4 s = {0.f, 0.f, 0.f, 0.f};
  for (int z = 0; z < KS; ++z)
    s += *(const f32x4*)(P + ((size_t)z * M + gr) * F + c4);
  f32x4 bv = *(const f32x4*)(bias + c4);
#pragma unroll
  for (int j = 0; j < 4; ++j) s[j] = elu_f(s[j] + bv[j]);
  if (outH) {
    u16x4 h, l;
#pragma unroll
    for (int j = 0; j < 4; ++j) {
      unsigned short hh, ll;
      split2(s[j], hh, ll);
      h[j] = hh; l[j] = ll;
    }
    *(u16x4*)(outH + (size_t)gr * F + c4) = h;
    *(u16x4*)(outL + (size_t)gr * F + c4) = l;
  } else if (outB) {
    u16x4 o;
#pragma unroll
    for (int j = 0; j < 4; ++j) o[j] = f32_bf16(s[j]);
    *(u16x4*)(outB + (size_t)gr * F + c4) = o;
  } else {
    *(f32x4*)(outF + (size_t)gr * F + c4) = s;
  }
}

// W2 [K=256, N] f32  ->  Wt [N, K] bf16
__global__ void w2_cast_transpose_kernel(const float* __restrict__ W2,
                                         unsigned short* __restrict__ Wt, int K, int N) {
  __shared__ float t[32][33];
  int c0 = blockIdx.x * 32, k0 = blockIdx.y * 32;
  int tx = threadIdx.x, ty = threadIdx.y;  // 32 x 8
  for (int j = ty; j < 32; j += 8) {
    int gk = k0 + j, gc = c0 + tx;
    t[j][tx] = (gk < K && gc < N) ? W2[(size_t)gk * N + gc] : 0.f;
  }
  __syncthreads();
  for (int j = ty; j < 32; j += 8) {
    int gc = c0 + j, gk = k0 + tx;
    if (gc < N && gk < K) Wt[(size_t)gc * K + gk] = f32_bf16(t[tx][j]);
  }
}

// Final layer GEMM: 128x128 tile, BK=64 double-buffered via global_load_lds.
// LDS layout per operand: [128 rows][8 chunks of 16B], per-row rotation
// pos = (c + row) & 7  -> every 8 consecutive lanes of a frag-read hit 8
// distinct 16B bank-quads (conflict-free). Stage decode is the inverse.
// MODE 0: emit per-(row, 64-col wave half) online-softmax partials (m,s).
// MODE 1: write out[gr][gc] = logit + bias - lse[gr].
template <int MODE>
__global__ __launch_bounds__(256) void gemm_final_kernel(
    const unsigned short* __restrict__ A, const unsigned short* __restrict__ Bt,
    const float* __restrict__ bias, const float* __restrict__ lse,
    float* __restrict__ outp, int M, int N) {
  __shared__ __align__(16) unsigned short lds[2][2][8192];  // [buf][A/B][128*64]
  int tid = threadIdx.x;
  int w = tid >> 6, l = tid & 63;
  int row0 = blockIdx.y * 128, col0 = blockIdx.x * 128;

  auto STAGE = [&](int buf, int kb) {
#pragma unroll
    for (int it = 0; it < 4; ++it) {
      int idx = it * 256 + tid;            // chunk id 0..1023
      int rr = idx >> 3, pos = idx & 7;
      int c = (pos - rr) & 7;
      int gra = row0 + rr; if (gra >= M) gra = M - 1;
      int grb = col0 + rr; if (grb >= N) grb = N - 1;
      gload_lds16(A + (size_t)gra * 256 + kb + c * 8, &lds[buf][0][(it * 256 + w * 64) * 8]);
      gload_lds16(Bt + (size_t)grb * 256 + kb + c * 8, &lds[buf][1][(it * 256 + w * 64) * 8]);
    }
  };

  int wm = w >> 1, wn = w & 1;
  int g = l >> 4, r = l & 15;

  f32x4 acc[4][4];
#pragma unroll
  for (int mi = 0; mi < 4; ++mi)
#pragma unroll
    for (int ni = 0; ni < 4; ++ni)
#pragma unroll
      for (int q = 0; q < 4; ++q) acc[mi][ni][q] = 0.f;

  STAGE(0, 0);
  __syncthreads();
#pragma unroll
  for (int ks = 0; ks < 4; ++ks) {
    int buf = ks & 1;
    if (ks < 3) STAGE(buf ^ 1, (ks + 1) * 64);
#pragma unroll
    for (int sub = 0; sub < 2; ++sub) {
      bf16x8 fa[4], fb[4];
#pragma unroll
      for (int mi = 0; mi < 4; ++mi) {
        int rA = wm * 64 + mi * 16 + r;
        fa[mi] = *(const bf16x8*)&lds[buf][0][rA * 64 + ((g + 4 * sub + rA) & 7) * 8];
      }
#pragma unroll
      for (int ni = 0; ni < 4; ++ni) {
        int rB = wn * 64 + ni * 16 + r;
        fb[ni] = *(const bf16x8*)&lds[buf][1][rB * 64 + ((g + 4 * sub + rB) & 7) * 8];
      }
#pragma unroll
      for (int mi = 0; mi < 4; ++mi)
#pragma unroll
        for (int ni = 0; ni < 4; ++ni)
          acc[mi][ni] = __builtin_amdgcn_mfma_f32_16x16x32_bf16(fb[ni], fa[mi], acc[mi][ni], 0, 0, 0);
    }
    __syncthreads();
  }

  if (MODE == 0) {
    float bb[4][4];
#pragma unroll
    for (int ni = 0; ni < 4; ++ni) {
      int gc0 = col0 + wn * 64 + ni * 16 + g * 4;
#pragma unroll
      for (int q = 0; q < 4; ++q)
        bb[ni][q] = (gc0 + q < N) ? bias[gc0 + q] : 0.f;
    }
#pragma unroll
    for (int mi = 0; mi < 4; ++mi) {
      int gr = row0 + wm * 64 + mi * 16 + r;
      float vv[4][4];
      float mloc = -3e38f;
#pragma unroll
      for (int ni = 0; ni < 4; ++ni) {
        int gc0 = col0 + wn * 64 + ni * 16 + g * 4;
#pragma unroll
        for (int q = 0; q < 4; ++q) {
          float v = (gc0 + q < N) ? (acc[mi][ni][q] + bb[ni][q]) : -3e38f;
          vv[ni][q] = v;
          mloc = fmaxf(mloc, v);
        }
      }
      float sloc = 0.f;
#pragma unroll
      for (int ni = 0; ni < 4; ++ni) {
        int gc0 = col0 + wn * 64 + ni * 16 + g * 4;
#pragma unroll
        for (int q = 0; q < 4; ++q)
          if (gc0 + q < N) sloc += __expf(vv[ni][q] - mloc);
      }
#pragma unroll
      for (int off = 16; off < 64; off <<= 1) {
        float mo = __shfl_xor(mloc, off);
        float so = __shfl_xor(sloc, off);
        float mn = fmaxf(mloc, mo);
        sloc = sloc * __expf(mloc - mn) + so * __expf(mo - mn);
        mloc = mn;
      }
      if (g == 0 && gr < M) {
        int hb = blockIdx.x * 2 + wn;
        *(float2*)(outp + 2 * ((size_t)hb * M + gr)) = make_float2(mloc, sloc);
      }
    }
  } else {
#pragma unroll
    for (int mi = 0; mi < 4; ++mi) {
      int gr = row0 + wm * 64 + mi * 16 + r;
      if (gr >= M) continue;
      float L = lse[gr];
      float* crow = outp + (size_t)gr * N;
#pragma unroll
      for (int ni = 0; ni < 4; ++ni) {
        int gc0 = col0 + wn * 64 + ni * 16 + g * 4;
        f32x4 v = acc[mi][ni];
        if (gc0 + 4 <= N) {
          f32x4 bv = *(const f32x4*)(bias + gc0);
#pragma unroll
          for (int q = 0; q < 4; ++q) v[q] = v[q] + bv[q] - L;
          *(f32x4*)(crow + gc0) = v;
        } else {
#pragma unroll
          for (int q = 0; q < 4; ++q)
            if (gc0 + q < N) crow[gc0 + q] = v[q] + bias[gc0 + q] - L;
        }
      }
    }
  }
}

// lse[row] = online-merge of NH (m,s) partials
__global__ __launch_bounds__(256) void lse_kernel(const float* __restrict__ stats,
                                                  float* __restrict__ lse, int M, int NH) {
  int row = blockIdx.x * 256 + threadIdx.x;
  if (row >= M) return;
  float m = -3e38f, s = 0.f;
  for (int hb = 0; hb < NH; ++hb) {
    float2 v = *(const float2*)(stats + 2 * ((size_t)hb * M + row));
    float mn = fmaxf(m, v.x);
    s = s * __expf(m - mn) + v.y * __expf(v.x - mn);
    m = mn;
  }
  lse[row] = m + logf(s);
}

extern "C" void kernel_launch(void* const* d_in, const int* in_sizes, int n_in,
                              void* d_out, int out_size, void* d_ws, size_t ws_size,
                              hipStream_t stream) {
  const int N = NND, E = NED;
  const float* x      = (const float*)d_in[0];
  const int*   ei     = (const int*)d_in[1];
  const float* pseudo = (const float*)d_in[2];
  const float* W_lin  = (const float*)d_in[3];
  const float* b_lin  = (const float*)d_in[4];
  const float* w1  = (const float*)d_in[5];
  const float* r1  = (const float*)d_in[6];
  const float* bi1 = (const float*)d_in[7];
  const float* w2  = (const float*)d_in[8];
  const float* r2  = (const float*)d_in[9];
  const float* bi2 = (const float*)d_in[10];
  const float* w3  = (const float*)d_in[11];
  const float* r3  = (const float*)d_in[12];
  const float* bi3 = (const float*)d_in[13];
  const float* W1  = (const float*)d_in[14];
  const float* b1  = (const float*)d_in[15];
  const float* W2  = (const float*)d_in[16];
  const float* b2  = (const float*)d_in[17];
  const int* erow = ei;
  const int* ecol = ei + E;

  // Scratch carved out of d_out (dead before pass C overwrites all of d_out)
  char* scratch = (char*)d_out;
  size_t off = 0;
  auto alloc = [&](size_t bytes) -> void* {
    void* p = scratch + off;
    off = (off + bytes + 255) & ~(size_t)255;
    return p;
  };
  unsigned short* Bh = (unsigned short*)alloc((size_t)N * 1664 * 2);
  unsigned short* Bl = (unsigned short*)alloc((size_t)N * 1664 * 2);
  float* h0     = (float*)alloc((size_t)N * 16 * 4);
  float* h1     = (float*)alloc((size_t)N * 32 * 4);
  float* h2     = (float*)alloc((size_t)N * 64 * 4);
  unsigned short* h3h = (unsigned short*)alloc((size_t)N * 128 * 2);
  unsigned short* h3l = (unsigned short*)alloc((size_t)N * 128 * 2);
  unsigned short* xh  = (unsigned short*)alloc((size_t)N * 544 * 2);
  unsigned short* xl  = (unsigned short*)alloc((size_t)N * 544 * 2);
  unsigned short* Wth = (unsigned short*)alloc((size_t)321024 * 2);
  unsigned short* Wtl = (unsigned short*)alloc((size_t)321024 * 2);
  float* Pbuf   = (float*)alloc((size_t)4 * N * 128 * 4);  // also fits 2*N*256
  float* stats  = (float*)alloc((size_t)108 * N * 2 * 4);
  float* ew     = (float*)alloc((size_t)E * 4 * 4);
  int*   ek     = (int*)alloc((size_t)E * 4 * 4);
  int*   deg    = (int*)alloc((size_t)N * 4);
  float* deginv = (float*)alloc((size_t)N * 4);
  int*   rowptr = (int*)alloc((size_t)(N + 1) * 4);
  int*   cursor = (int*)alloc((size_t)N * 4);
  int*   csr    = (int*)alloc((size_t)E * 4);

  // Buffers alive during pass C go in d_ws
  unsigned short* h4b = (unsigned short*)d_ws;                                 // N*256 bf16
  unsigned short* W2t = (unsigned short*)((char*)d_ws + (size_t)N * 256 * 2);  // N*256 bf16
  float* lse = (float*)((char*)d_ws + (size_t)N * 256 * 4);                    // N f32

  // ---- graph prep ----
  zero_int_kernel<<<(N + 255) / 256, 256, 0, stream>>>(deg, N);
  edge_prep_kernel<<<(E + 255) / 256, 256, 0, stream>>>(erow, pseudo, ew, ek, deg, E);
  scan_kernel<<<1, 1024, 0, stream>>>(deg, rowptr, cursor, deginv, N);
  csr_fill_kernel<<<(E + 255) / 256, 256, 0, stream>>>(erow, cursor, csr, E);

  // ---- weight splits + x split ----
  weights_prep_kernel<<<323, 256, 0, stream>>>(W_lin, w1, r1, w2, r2, w3, r3, W1, Wth, Wtl);
  split_kernel<<<(N * 136 + 255) / 256, 256, 0, stream>>>(x, xh, xl, N * 136);  // N*544/4

  auto cgrid = [](int M_, int F_) { return dim3((M_ * (F_ / 4) + 255) / 256); };

  // ---- stage 0: h0 = elu(x @ W_lin + b_lin) ----
  gemm_x3_partial_kernel<16><<<dim3(1, 108, 4), 256, 0, stream>>>(xh, xl, Wth + 0, Wtl + 0, Pbuf, N, 544, 16, 4);
  combine_elu_kernel<<<cgrid(N, 16), 256, 0, stream>>>(Pbuf, b_lin, h0, nullptr, nullptr, nullptr, N, 16, 4);

  // ---- spline layer 1 (16 -> 32), Kd = 416 ----
  b_build_kernel<<<N, 64, 26 * 16 * 4, stream>>>(h0, ecol, ew, ek, rowptr, csr, deginv, Bh, Bl, 16);
  gemm_x3_partial_kernel<32><<<dim3(1, 108, 4), 256, 0, stream>>>(Bh, Bl, Wth + 8704, Wtl + 8704, Pbuf, N, 416, 32, 4);
  combine_elu_kernel<<<cgrid(N, 32), 256, 0, stream>>>(Pbuf, bi1, h1, nullptr, nullptr, nullptr, N, 32, 4);

  // ---- spline layer 2 (32 -> 64), Kd = 832 ----
  b_build_kernel<<<N, 128, 26 * 32 * 4, stream>>>(h1, ecol, ew, ek, rowptr, csr, deginv, Bh, Bl, 32);
  gemm_x3_partial_kernel<64><<<dim3(1, 108, 4), 256, 0, stream>>>(Bh, Bl, Wth + 22016, Wtl + 22016, Pbuf, N, 832, 64, 4);
  combine_elu_kernel<<<cgrid(N, 64), 256, 0, stream>>>(Pbuf, bi2, h2, nullptr, nullptr, nullptr, N, 64, 4);

  // ---- spline layer 3 (64 -> 128), Kd = 1664 ----
  b_build_kernel<<<N, 256, 26 * 64 * 4, stream>>>(h2, ecol, ew, ek, rowptr, csr, deginv, Bh, Bl, 64);
  gemm_x3_partial_kernel<128><<<dim3(1, 108, 4), 256, 0, stream>>>(Bh, Bl, Wth + 75264, Wtl + 75264, Pbuf, N, 1664, 128, 4);
  combine_elu_kernel<<<cgrid(N, 128), 256, 0, stream>>>(Pbuf, bi3, nullptr, nullptr, h3h, h3l, N, 128, 4);

  // ---- stage 4: h4 = elu(h3 @ W1 + b1) -> bf16 ----
  gemm_x3_partial_kernel<128><<<dim3(2, 108, 2), 256, 0, stream>>>(h3h, h3l, Wth + 288256, Wtl + 288256, Pbuf, N, 128, 256, 2);
  combine_elu_kernel<<<cgrid(N, 256), 256, 0, stream>>>(Pbuf, b1, nullptr, h4b, nullptr, nullptr, N, 256, 2);

  // ---- W2 -> bf16 transposed ----
  w2_cast_transpose_kernel<<<dim3(216, 8), dim3(32, 8), 0, stream>>>(W2, W2t, 256, N);

  // ---- pass A: softmax partials ----
  gemm_final_kernel<0><<<dim3(54, 54), 256, 0, stream>>>(h4b, W2t, b2, nullptr, stats, N, N);

  // ---- pass B: lse per row ----
  lse_kernel<<<(N + 255) / 256, 256, 0, stream>>>(stats, lse, N, 108);

  // ---- pass C: recompute logits, write logit - lse ----
  gemm_final_kernel<1><<<dim3(54, 54), 256, 0, stream>>>(h4b, W2t, b2, lse, (float*)d_out, N, N);

  (void)in_sizes; (void)n_in; (void)out_size; (void)ws_size;
}

// Round 7
// 315.493 us; speedup vs baseline: 1.5617x; 1.2185x over previous
//
#include <hip/hip_runtime.h>
#include <hip/hip_bf16.h>

#define NND 6890
#define NED 41340

typedef __bf16 bf16x8 __attribute__((ext_vector_type(8)));
typedef float f32x4 __attribute__((ext_vector_type(4)));
typedef unsigned short u16x4 __attribute__((ext_vector_type(4)));

__device__ inline unsigned short f32_bf16(float f) {
  unsigned int u = __float_as_uint(f);
  unsigned int r = (u + 0x7FFFu + ((u >> 16) & 1u)) >> 16;
  return (unsigned short)r;
}
__device__ inline void split2(float v, unsigned short& hi, unsigned short& lo) {
  unsigned short h = f32_bf16(v);
  float hf = __uint_as_float((unsigned int)h << 16);
  hi = h;
  lo = f32_bf16(v - hf);
}
__device__ inline float elu_f(float v) { return v > 0.f ? v : (expf(v) - 1.f); }

__device__ __forceinline__ void gload_lds16(const void* g, void* l) {
  __builtin_amdgcn_global_load_lds((const __attribute__((address_space(1))) void*)g,
                                   (__attribute__((address_space(3))) void*)l, 16, 0, 0);
}

__global__ void zero_int_kernel(int* p, int n) {
  int i = blockIdx.x * blockDim.x + threadIdx.x;
  if (i < n) p[i] = 0;
}

__global__ void edge_prep_kernel(const int* __restrict__ erow, const float* __restrict__ pseudo,
                                 float* __restrict__ ew, int* __restrict__ ek,
                                 int* __restrict__ deg, int E) {
  int e = blockIdx.x * blockDim.x + threadIdx.x;
  if (e >= E) return;
  float p0 = pseudo[2 * e + 0] * 4.0f;
  float p1 = pseudo[2 * e + 1] * 4.0f;
  int i0 = (int)floorf(p0); i0 = i0 < 0 ? 0 : (i0 > 3 ? 3 : i0);
  int i1 = (int)floorf(p1); i1 = i1 < 0 ? 0 : (i1 > 3 ? 3 : i1);
  float f0 = p0 - (float)i0, f1 = p1 - (float)i1;
  ew[4 * e + 0] = (1.f - f0) * (1.f - f1);
  ew[4 * e + 1] = f0 * (1.f - f1);
  ew[4 * e + 2] = (1.f - f0) * f1;
  ew[4 * e + 3] = f0 * f1;
  int b = i0 + 5 * i1;
  ek[4 * e + 0] = b; ek[4 * e + 1] = b + 1; ek[4 * e + 2] = b + 5; ek[4 * e + 3] = b + 6;
  atomicAdd(&deg[erow[e]], 1);
}

__global__ void scan_kernel(const int* __restrict__ deg, int* __restrict__ rowptr,
                            int* __restrict__ cursor, float* __restrict__ deginv, int n) {
  __shared__ int part[1024];
  int t = threadIdx.x;
  int CH = (n + 1023) >> 10;
  int base = t * CH;
  int s = 0;
  for (int j = 0; j < CH; ++j) { int i = base + j; if (i < n) s += deg[i]; }
  part[t] = s;
  __syncthreads();
  for (int off = 1; off < 1024; off <<= 1) {
    int v = (t >= off) ? part[t - off] : 0;
    __syncthreads();
    part[t] += v;
    __syncthreads();
  }
  int run = (t == 0) ? 0 : part[t - 1];
  for (int j = 0; j < CH; ++j) {
    int i = base + j;
    if (i < n) {
      rowptr[i] = run; cursor[i] = run;
      int d = deg[i];
      deginv[i] = 1.0f / fmaxf((float)d, 1.0f);
      run += d;
    }
  }
  if (t == 1023) rowptr[n] = part[1023];
}

__global__ void csr_fill_kernel(const int* __restrict__ erow, int* __restrict__ cursor,
                                int* __restrict__ csr, int E) {
  int e = blockIdx.x * blockDim.x + threadIdx.x;
  if (e >= E) return;
  int slot = atomicAdd(&cursor[erow[e]], 1);
  csr[slot] = e;
}

// src f32 [n4*4] -> hi/lo bf16 planes
__global__ void split_kernel(const float* __restrict__ src, unsigned short* __restrict__ oh,
                             unsigned short* __restrict__ ol, int n4) {
  int i = blockIdx.x * 256 + threadIdx.x;
  if (i >= n4) return;
  f32x4 v = *(const f32x4*)(src + 4 * i);
  u16x4 h, l;
#pragma unroll
  for (int j = 0; j < 4; ++j) {
    unsigned short hh, ll;
    split2(v[j], hh, ll);
    h[j] = hh; l[j] = ll;
  }
  *(u16x4*)(oh + 4 * i) = h;
  *(u16x4*)(ol + 4 * i) = l;
}

// B-row build, atomic-free: 4 edge-phase LDS planes (j = tid/Fin), each thread
// owns column i of plane j -> plain f32 adds, no races, no in-loop barriers.
// Output: Bh/Bl bf16 planes [N][Kd=26*Fin]; slots scaled by deginv, root appended.
__global__ void b_build_kernel(const float* __restrict__ x, const int* __restrict__ ecol,
                               const float* __restrict__ ew4, const int* __restrict__ ek4,
                               const int* __restrict__ rowptr, const int* __restrict__ csr,
                               const float* __restrict__ deginv,
                               unsigned short* __restrict__ Bh, unsigned short* __restrict__ Bl,
                               int Fin) {
  extern __shared__ float lds[];  // 4 planes x 25*Fin floats
  int r = blockIdx.x;
  int T = blockDim.x;  // 4*Fin
  int tid = threadIdx.x;
  int nb = 25 * Fin;
  int j = tid / Fin;
  int i = tid - j * Fin;
  float* plane = lds + j * nb;
  for (int t = tid; t < 4 * nb; t += T) lds[t] = 0.f;
  __syncthreads();
  int p0 = rowptr[r], p1 = rowptr[r + 1];
  for (int p = p0 + j; p < p1; p += 4) {
    int e = csr[p];
    int c = ecol[e];
    float xv = x[(size_t)c * Fin + i];
    f32x4 wv = *(const f32x4*)(ew4 + 4 * e);
    int4 kv = *(const int4*)(ek4 + 4 * e);
    plane[kv.x * Fin + i] += wv[0] * xv;
    plane[kv.y * Fin + i] += wv[1] * xv;
    plane[kv.z * Fin + i] += wv[2] * xv;
    plane[kv.w * Fin + i] += wv[3] * xv;
  }
  __syncthreads();
  float dinv = deginv[r];
  int tot = nb + Fin;  // = 26*Fin = Kd
  for (int t = tid; t < tot; t += T) {
    float v;
    if (t < nb)
      v = (lds[t] + lds[nb + t] + lds[2 * nb + t] + lds[3 * nb + t]) * dinv;
    else
      v = x[(size_t)r * Fin + (t - nb)];
    unsigned short h, l;
    split2(v, h, l);
    Bh[(size_t)r * tot + t] = h;
    Bl[(size_t)r * tot + t] = l;
  }
}

// All weight splits (hi/lo bf16, transposed to [F, ldt]) in one kernel.
__global__ void weights_prep_kernel(const float* __restrict__ W_lin, const float* __restrict__ w1,
                                    const float* __restrict__ r1, const float* __restrict__ w2,
                                    const float* __restrict__ r2, const float* __restrict__ w3,
                                    const float* __restrict__ r3, const float* __restrict__ W1,
                                    unsigned short* __restrict__ Th, unsigned short* __restrict__ Tl) {
  const int tstart[9] = {0, 17, 30, 31, 81, 83, 283, 291, 323};
  const int jK[8]    = {544, 400, 16, 800, 32, 1600, 64, 128};
  const int jF[8]    = {16, 32, 32, 64, 64, 128, 128, 256};
  const int jldt[8]  = {544, 416, 416, 832, 832, 1664, 1664, 128};
  const int jkoff[8] = {0, 0, 400, 0, 800, 0, 1600, 0};
  const int jdst[8]  = {0, 8704, 8704, 22016, 22016, 75264, 75264, 288256};
  int b = blockIdx.x;
  int job = 0;
  while (job < 7 && b >= tstart[job + 1]) ++job;
  int t = b - tstart[job];
  int fxc = (jF[job] + 31) >> 5;
  int kt = t / fxc, ft = t % fxc;
  const float* src;
  switch (job) {
    case 0: src = W_lin; break;
    case 1: src = w1; break;
    case 2: src = r1; break;
    case 3: src = w2; break;
    case 4: src = r2; break;
    case 5: src = w3; break;
    case 6: src = r3; break;
    default: src = W1; break;
  }
  int K = jK[job], F = jF[job], ldt = jldt[job], koff = jkoff[job];
  unsigned short* th = Th + jdst[job];
  unsigned short* tl = Tl + jdst[job];
  int k0 = kt * 32, c0 = ft * 32;
  __shared__ float tbuf[32][33];
  int tx = threadIdx.x & 31, ty = threadIdx.x >> 5;  // 32 x 8
  for (int j = ty; j < 32; j += 8) {
    int gk = k0 + j, gc = c0 + tx;
    tbuf[j][tx] = (gk < K && gc < F) ? src[(size_t)gk * F + gc] : 0.f;
  }
  __syncthreads();
  for (int j = ty; j < 32; j += 8) {
    int gc = c0 + j, gk = k0 + tx;
    if (gc < F && gk < K) {
      unsigned short h, lo2;
      split2(tbuf[tx][j], h, lo2);
      th[(size_t)gc * ldt + koff + gk] = h;
      tl[(size_t)gc * ldt + koff + gk] = lo2;
    }
  }
}

// Partial GEMM (bf16x3) over K-slice z: P[z][M][F] = A @ W.
// A, W pre-split bf16 planes; staging via global_load_lds with per-row
// 4-chunk rotation (2-way banks = free). 64-row A tile, BN-col W tile, BK=32.
template <int BN>
__global__ __launch_bounds__(256) void gemm_x3_partial_kernel(
    const unsigned short* __restrict__ Ah, const unsigned short* __restrict__ Al,
    const unsigned short* __restrict__ Wh, const unsigned short* __restrict__ Wl,
    float* __restrict__ P, int M, int Kd, int F, int KS) {
  constexpr int AE = 64 * 32;   // elements per A plane tile
  constexpr int WE = BN * 32;
  __shared__ __align__(16) unsigned short lds[2][2 * AE + 2 * WE];
  int tid = threadIdx.x;
  int wave = tid >> 6, lane = tid & 63;
  int g = lane >> 4, r = lane & 15;
  int row0 = blockIdx.y * 64;
  int col0 = blockIdx.x * BN;
  int z = blockIdx.z;
  int nt = Kd >> 5;
  int ta = z * nt / KS, tb = (z + 1) * nt / KS;

  auto STAGE = [&](int buf, int kb) {
    {  // A tiles: 256 chunks; row = idx>>2, pos = idx&3, src chunk = (pos-row)&3
      int rr = tid >> 2, pos = tid & 3;
      int c = (pos - rr) & 3;
      int gra = row0 + rr; if (gra >= M) gra = M - 1;
      size_t so = (size_t)gra * Kd + kb + c * 8;
      gload_lds16(Ah + so, &lds[buf][wave * 512]);
      gload_lds16(Al + so, &lds[buf][AE + wave * 512]);
    }
#pragma unroll
    for (int it = 0; it < (4 * BN + 255) / 256; ++it) {
      int idx = it * 256 + tid;
      if (idx < 4 * BN) {
        int rr = idx >> 2, pos = idx & 3;
        int c = (pos - rr) & 3;
        size_t so = (size_t)(col0 + rr) * Kd + kb + c * 8;
        gload_lds16(Wh + so, &lds[buf][2 * AE + (it * 256 + wave * 64) * 8]);
        gload_lds16(Wl + so, &lds[buf][2 * AE + WE + (it * 256 + wave * 64) * 8]);
      }
    }
  };

  constexpr int NF = BN / 16;
  f32x4 acc[NF];
#pragma unroll
  for (int n = 0; n < NF; ++n)
#pragma unroll
    for (int q = 0; q < 4; ++q) acc[n][q] = 0.f;

  int n = tb - ta;
  int rA = wave * 16 + r;
  int aoff = rA * 32 + ((g + rA) & 3) * 8;

  STAGE(0, ta * 32);
  __syncthreads();
  for (int tt = 0; tt < n; ++tt) {
    int buf = tt & 1;
    if (tt + 1 < n) STAGE(buf ^ 1, (ta + tt + 1) * 32);
    bf16x8 fah = *(const bf16x8*)&lds[buf][aoff];
    bf16x8 fal = *(const bf16x8*)&lds[buf][AE + aoff];
#pragma unroll
    for (int nn = 0; nn < NF; ++nn) {
      int rW = nn * 16 + r;
      int woff = rW * 32 + ((g + rW) & 3) * 8;
      bf16x8 fbh = *(const bf16x8*)&lds[buf][2 * AE + woff];
      bf16x8 fbl = *(const bf16x8*)&lds[buf][2 * AE + WE + woff];
      acc[nn] = __builtin_amdgcn_mfma_f32_16x16x32_bf16(fah, fbh, acc[nn], 0, 0, 0);
      acc[nn] = __builtin_amdgcn_mfma_f32_16x16x32_bf16(fal, fbh, acc[nn], 0, 0, 0);
      acc[nn] = __builtin_amdgcn_mfma_f32_16x16x32_bf16(fah, fbl, acc[nn], 0, 0, 0);
    }
    __syncthreads();
  }
#pragma unroll
  for (int nn = 0; nn < NF; ++nn) {
    int gc = col0 + nn * 16 + r;
#pragma unroll
    for (int q = 0; q < 4; ++q) {
      int gr = row0 + wave * 16 + g * 4 + q;
      if (gr < M) P[((size_t)z * M + gr) * F + gc] = acc[nn][q];
    }
  }
}

// out = elu(sum_z P[z] + bias); f32, bf16, or hi/lo-plane output
__global__ __launch_bounds__(256) void combine_elu_kernel(
    const float* __restrict__ P, const float* __restrict__ bias,
    float* __restrict__ outF, unsigned short* __restrict__ outB,
    unsigned short* __restrict__ outH, unsigned short* __restrict__ outL,
    int M, int F, int KS) {
  int i4 = blockIdx.x * 256 + threadIdx.x;
  int fv = F >> 2;
  int total = M * fv;
  if (i4 >= total) return;
  int gr = i4 / fv, c4 = (i4 - gr * fv) * 4;
  f32x4 s = {0.f, 0.f, 0.f, 0.f};
  for (int z = 0; z < KS; ++z)
    s += *(const f32x4*)(P + ((size_t)z * M + gr) * F + c4);
  f32x4 bv = *(const f32x4*)(bias + c4);
#pragma unroll
  for (int j = 0; j < 4; ++j) s[j] = elu_f(s[j] + bv[j]);
  if (outH) {
    u16x4 h, l;
#pragma unroll
    for (int j = 0; j < 4; ++j) {
      unsigned short hh, ll;
      split2(s[j], hh, ll);
      h[j] = hh; l[j] = ll;
    }
    *(u16x4*)(outH + (size_t)gr * F + c4) = h;
    *(u16x4*)(outL + (size_t)gr * F + c4) = l;
  } else if (outB) {
    u16x4 o;
#pragma unroll
    for (int j = 0; j < 4; ++j) o[j] = f32_bf16(s[j]);
    *(u16x4*)(outB + (size_t)gr * F + c4) = o;
  } else {
    *(f32x4*)(outF + (size_t)gr * F + c4) = s;
  }
}

// W2 [K=256, N] f32  ->  Wt [N, K] bf16
__global__ void w2_cast_transpose_kernel(const float* __restrict__ W2,
                                         unsigned short* __restrict__ Wt, int K, int N) {
  __shared__ float t[32][33];
  int c0 = blockIdx.x * 32, k0 = blockIdx.y * 32;
  int tx = threadIdx.x, ty = threadIdx.y;  // 32 x 8
  for (int j = ty; j < 32; j += 8) {
    int gk = k0 + j, gc = c0 + tx;
    t[j][tx] = (gk < K && gc < N) ? W2[(size_t)gk * N + gc] : 0.f;
  }
  __syncthreads();
  for (int j = ty; j < 32; j += 8) {
    int gc = c0 + j, gk = k0 + tx;
    if (gc < N && gk < K) Wt[(size_t)gc * K + gk] = f32_bf16(t[tx][j]);
  }
}

// Final layer GEMM: 128x128 tile, BK=64 double-buffered via global_load_lds,
// per-row 8-chunk rotation (conflict-free frag reads).
// MODE 0: emit per-(row, 64-col wave half) online-softmax partials (m,s).
// MODE 1: stash acc in LDS (col-swizzled), then fully-coalesced row-major
//         f32x4 stores of logit + bias - lse (fixes 16B partial-line writes).
template <int MODE>
__global__ __launch_bounds__(256) void gemm_final_kernel(
    const unsigned short* __restrict__ A, const unsigned short* __restrict__ Bt,
    const float* __restrict__ bias, const float* __restrict__ lse,
    float* __restrict__ outp, int M, int N) {
  __shared__ __align__(16) unsigned short lds[2][2][8192];  // 64 KB
  int tid = threadIdx.x;
  int w = tid >> 6, l = tid & 63;
  int row0 = blockIdx.y * 128, col0 = blockIdx.x * 128;

  auto STAGE = [&](int buf, int kb) {
#pragma unroll
    for (int it = 0; it < 4; ++it) {
      int idx = it * 256 + tid;            // chunk id 0..1023
      int rr = idx >> 3, pos = idx & 7;
      int c = (pos - rr) & 7;
      int gra = row0 + rr; if (gra >= M) gra = M - 1;
      int grb = col0 + rr; if (grb >= N) grb = N - 1;
      gload_lds16(A + (size_t)gra * 256 + kb + c * 8, &lds[buf][0][(it * 256 + w * 64) * 8]);
      gload_lds16(Bt + (size_t)grb * 256 + kb + c * 8, &lds[buf][1][(it * 256 + w * 64) * 8]);
    }
  };

  int wm = w >> 1, wn = w & 1;
  int g = l >> 4, r = l & 15;

  f32x4 acc[4][4];
#pragma unroll
  for (int mi = 0; mi < 4; ++mi)
#pragma unroll
    for (int ni = 0; ni < 4; ++ni)
#pragma unroll
      for (int q = 0; q < 4; ++q) acc[mi][ni][q] = 0.f;

  STAGE(0, 0);
  __syncthreads();
#pragma unroll
  for (int ks = 0; ks < 4; ++ks) {
    int buf = ks & 1;
    if (ks < 3) STAGE(buf ^ 1, (ks + 1) * 64);
#pragma unroll
    for (int sub = 0; sub < 2; ++sub) {
      bf16x8 fa[4], fb[4];
#pragma unroll
      for (int mi = 0; mi < 4; ++mi) {
        int rA = wm * 64 + mi * 16 + r;
        fa[mi] = *(const bf16x8*)&lds[buf][0][rA * 64 + ((g + 4 * sub + rA) & 7) * 8];
      }
#pragma unroll
      for (int ni = 0; ni < 4; ++ni) {
        int rB = wn * 64 + ni * 16 + r;
        fb[ni] = *(const bf16x8*)&lds[buf][1][rB * 64 + ((g + 4 * sub + rB) & 7) * 8];
      }
#pragma unroll
      for (int mi = 0; mi < 4; ++mi)
#pragma unroll
        for (int ni = 0; ni < 4; ++ni)
          acc[mi][ni] = __builtin_amdgcn_mfma_f32_16x16x32_bf16(fb[ni], fa[mi], acc[mi][ni], 0, 0, 0);
    }
    __syncthreads();
  }

  if (MODE == 0) {
    float bb[4][4];
#pragma unroll
    for (int ni = 0; ni < 4; ++ni) {
      int gc0 = col0 + wn * 64 + ni * 16 + g * 4;
#pragma unroll
      for (int q = 0; q < 4; ++q)
        bb[ni][q] = (gc0 + q < N) ? bias[gc0 + q] : 0.f;
    }
#pragma unroll
    for (int mi = 0; mi < 4; ++mi) {
      int gr = row0 + wm * 64 + mi * 16 + r;
      float vv[4][4];
      float mloc = -3e38f;
#pragma unroll
      for (int ni = 0; ni < 4; ++ni) {
        int gc0 = col0 + wn * 64 + ni * 16 + g * 4;
#pragma unroll
        for (int q = 0; q < 4; ++q) {
          float v = (gc0 + q < N) ? (acc[mi][ni][q] + bb[ni][q]) : -3e38f;
          vv[ni][q] = v;
          mloc = fmaxf(mloc, v);
        }
      }
      float sloc = 0.f;
#pragma unroll
      for (int ni = 0; ni < 4; ++ni) {
        int gc0 = col0 + wn * 64 + ni * 16 + g * 4;
#pragma unroll
        for (int q = 0; q < 4; ++q)
          if (gc0 + q < N) sloc += __expf(vv[ni][q] - mloc);
      }
#pragma unroll
      for (int off = 16; off < 64; off <<= 1) {
        float mo = __shfl_xor(mloc, off);
        float so = __shfl_xor(sloc, off);
        float mn = fmaxf(mloc, mo);
        sloc = sloc * __expf(mloc - mn) + so * __expf(mo - mn);
        mloc = mn;
      }
      if (g == 0 && gr < M) {
        int hb = blockIdx.x * 2 + wn;
        *(float2*)(outp + 2 * ((size_t)hb * M + gr)) = make_float2(mloc, sloc);
      }
    }
  } else {
    // acc -> LDS (col-swizzled u = (chunk + row)&15), then coalesced stores
    float* fsc = (float*)&lds[0][0][0];   // 16384 floats = 4 regions x 4096
    float* wbase = fsc + w * 4096;
#pragma unroll
    for (int mi = 0; mi < 4; ++mi) {
      int rr = mi * 16 + r;
#pragma unroll
      for (int ni = 0; ni < 4; ++ni) {
        int u = (ni * 4 + g + rr) & 15;
        *(f32x4*)(wbase + rr * 64 + u * 4) = acc[mi][ni];
      }
    }
    __syncthreads();
#pragma unroll
    for (int t = 0; t < 16; ++t) {
      int unit = t * 256 + tid;           // 128 rows x 32 f32x4-chunks
      int rowi = unit >> 5, ch = unit & 31;
      int gr = row0 + rowi;
      if (gr >= M) continue;
      int reg = ((rowi >> 6) << 1) + (ch >> 4);
      int rr = rowi & 63;
      int u = ((ch & 15) + rr) & 15;
      f32x4 v = *(const f32x4*)(fsc + reg * 4096 + rr * 64 + u * 4);
      float L = lse[gr];
      int gc0 = col0 + ch * 4;
      if (gc0 + 4 <= N) {
        f32x4 bv = *(const f32x4*)(bias + gc0);
#pragma unroll
        for (int q = 0; q < 4; ++q) v[q] = v[q] + bv[q] - L;
        *(f32x4*)(outp + (size_t)gr * N + gc0) = v;
      } else {
#pragma unroll
        for (int q = 0; q < 4; ++q)
          if (gc0 + q < N) outp[(size_t)gr * N + gc0 + q] = v[q] + bias[gc0 + q] - L;
      }
    }
  }
}

// lse[row] = online-merge of NH (m,s) partials
__global__ __launch_bounds__(256) void lse_kernel(const float* __restrict__ stats,
                                                  float* __restrict__ lse, int M, int NH) {
  int row = blockIdx.x * 256 + threadIdx.x;
  if (row >= M) return;
  float m = -3e38f, s = 0.f;
  for (int hb = 0; hb < NH; ++hb) {
    float2 v = *(const float2*)(stats + 2 * ((size_t)hb * M + row));
    float mn = fmaxf(m, v.x);
    s = s * __expf(m - mn) + v.y * __expf(v.x - mn);
    m = mn;
  }
  lse[row] = m + logf(s);
}

extern "C" void kernel_launch(void* const* d_in, const int* in_sizes, int n_in,
                              void* d_out, int out_size, void* d_ws, size_t ws_size,
                              hipStream_t stream) {
  const int N = NND, E = NED;
  const float* x      = (const float*)d_in[0];
  const int*   ei     = (const int*)d_in[1];
  const float* pseudo = (const float*)d_in[2];
  const float* W_lin  = (const float*)d_in[3];
  const float* b_lin  = (const float*)d_in[4];
  const float* w1  = (const float*)d_in[5];
  const float* r1  = (const float*)d_in[6];
  const float* bi1 = (const float*)d_in[7];
  const float* w2  = (const float*)d_in[8];
  const float* r2  = (const float*)d_in[9];
  const float* bi2 = (const float*)d_in[10];
  const float* w3  = (const float*)d_in[11];
  const float* r3  = (const float*)d_in[12];
  const float* bi3 = (const float*)d_in[13];
  const float* W1  = (const float*)d_in[14];
  const float* b1  = (const float*)d_in[15];
  const float* W2  = (const float*)d_in[16];
  const float* b2  = (const float*)d_in[17];
  const int* erow = ei;
  const int* ecol = ei + E;

  // Scratch carved out of d_out (dead before pass C overwrites all of d_out)
  char* scratch = (char*)d_out;
  size_t off = 0;
  auto alloc = [&](size_t bytes) -> void* {
    void* p = scratch + off;
    off = (off + bytes + 255) & ~(size_t)255;
    return p;
  };
  unsigned short* Bh = (unsigned short*)alloc((size_t)N * 1664 * 2);
  unsigned short* Bl = (unsigned short*)alloc((size_t)N * 1664 * 2);
  float* h0     = (float*)alloc((size_t)N * 16 * 4);
  float* h1     = (float*)alloc((size_t)N * 32 * 4);
  float* h2     = (float*)alloc((size_t)N * 64 * 4);
  unsigned short* h3h = (unsigned short*)alloc((size_t)N * 128 * 2);
  unsigned short* h3l = (unsigned short*)alloc((size_t)N * 128 * 2);
  unsigned short* xh  = (unsigned short*)alloc((size_t)N * 544 * 2);
  unsigned short* xl  = (unsigned short*)alloc((size_t)N * 544 * 2);
  unsigned short* Wth = (unsigned short*)alloc((size_t)321024 * 2);
  unsigned short* Wtl = (unsigned short*)alloc((size_t)321024 * 2);
  float* Pbuf   = (float*)alloc((size_t)4 * N * 128 * 4);  // also fits 2*N*256
  float* stats  = (float*)alloc((size_t)108 * N * 2 * 4);
  float* ew     = (float*)alloc((size_t)E * 4 * 4);
  int*   ek     = (int*)alloc((size_t)E * 4 * 4);
  int*   deg    = (int*)alloc((size_t)N * 4);
  float* deginv = (float*)alloc((size_t)N * 4);
  int*   rowptr = (int*)alloc((size_t)(N + 1) * 4);
  int*   cursor = (int*)alloc((size_t)N * 4);
  int*   csr    = (int*)alloc((size_t)E * 4);

  // Buffers alive during pass C go in d_ws
  unsigned short* h4b = (unsigned short*)d_ws;                                 // N*256 bf16
  unsigned short* W2t = (unsigned short*)((char*)d_ws + (size_t)N * 256 * 2);  // N*256 bf16
  float* lse = (float*)((char*)d_ws + (size_t)N * 256 * 4);                    // N f32

  // ---- graph prep ----
  zero_int_kernel<<<(N + 255) / 256, 256, 0, stream>>>(deg, N);
  edge_prep_kernel<<<(E + 255) / 256, 256, 0, stream>>>(erow, pseudo, ew, ek, deg, E);
  scan_kernel<<<1, 1024, 0, stream>>>(deg, rowptr, cursor, deginv, N);
  csr_fill_kernel<<<(E + 255) / 256, 256, 0, stream>>>(erow, cursor, csr, E);

  // ---- weight splits + x split ----
  weights_prep_kernel<<<323, 256, 0, stream>>>(W_lin, w1, r1, w2, r2, w3, r3, W1, Wth, Wtl);
  split_kernel<<<(N * 136 + 255) / 256, 256, 0, stream>>>(x, xh, xl, N * 136);  // N*544/4

  auto cgrid = [](int M_, int F_) { return dim3((M_ * (F_ / 4) + 255) / 256); };

  // ---- stage 0: h0 = elu(x @ W_lin + b_lin) ----
  gemm_x3_partial_kernel<16><<<dim3(1, 108, 4), 256, 0, stream>>>(xh, xl, Wth + 0, Wtl + 0, Pbuf, N, 544, 16, 4);
  combine_elu_kernel<<<cgrid(N, 16), 256, 0, stream>>>(Pbuf, b_lin, h0, nullptr, nullptr, nullptr, N, 16, 4);

  // ---- spline layer 1 (16 -> 32), Kd = 416 ----
  b_build_kernel<<<N, 64, 4 * 25 * 16 * 4, stream>>>(h0, ecol, ew, ek, rowptr, csr, deginv, Bh, Bl, 16);
  gemm_x3_partial_kernel<32><<<dim3(1, 108, 4), 256, 0, stream>>>(Bh, Bl, Wth + 8704, Wtl + 8704, Pbuf, N, 416, 32, 4);
  combine_elu_kernel<<<cgrid(N, 32), 256, 0, stream>>>(Pbuf, bi1, h1, nullptr, nullptr, nullptr, N, 32, 4);

  // ---- spline layer 2 (32 -> 64), Kd = 832 ----
  b_build_kernel<<<N, 128, 4 * 25 * 32 * 4, stream>>>(h1, ecol, ew, ek, rowptr, csr, deginv, Bh, Bl, 32);
  gemm_x3_partial_kernel<64><<<dim3(1, 108, 4), 256, 0, stream>>>(Bh, Bl, Wth + 22016, Wtl + 22016, Pbuf, N, 832, 64, 4);
  combine_elu_kernel<<<cgrid(N, 64), 256, 0, stream>>>(Pbuf, bi2, h2, nullptr, nullptr, nullptr, N, 64, 4);

  // ---- spline layer 3 (64 -> 128), Kd = 1664 ----
  b_build_kernel<<<N, 256, 4 * 25 * 64 * 4, stream>>>(h2, ecol, ew, ek, rowptr, csr, deginv, Bh, Bl, 64);
  gemm_x3_partial_kernel<128><<<dim3(1, 108, 4), 256, 0, stream>>>(Bh, Bl, Wth + 75264, Wtl + 75264, Pbuf, N, 1664, 128, 4);
  combine_elu_kernel<<<cgrid(N, 128), 256, 0, stream>>>(Pbuf, bi3, nullptr, nullptr, h3h, h3l, N, 128, 4);

  // ---- stage 4: h4 = elu(h3 @ W1 + b1) -> bf16 ----
  gemm_x3_partial_kernel<128><<<dim3(2, 108, 2), 256, 0, stream>>>(h3h, h3l, Wth + 288256, Wtl + 288256, Pbuf, N, 128, 256, 2);
  combine_elu_kernel<<<cgrid(N, 256), 256, 0, stream>>>(Pbuf, b1, nullptr, h4b, nullptr, nullptr, N, 256, 2);

  // ---- W2 -> bf16 transposed ----
  w2_cast_transpose_kernel<<<dim3(216, 8), dim3(32, 8), 0, stream>>>(W2, W2t, 256, N);

  // ---- pass A: softmax partials ----
  gemm_final_kernel<0><<<dim3(54, 54), 256, 0, stream>>>(h4b, W2t, b2, nullptr, stats, N, N);

  // ---- pass B: lse per row ----
  lse_kernel<<<(N + 255) / 256, 256, 0, stream>>>(stats, lse, N, 108);

  // ---- pass C: recompute logits, write logit - lse ----
  gemm_final_kernel<1><<<dim3(54, 54), 256, 0, stream>>>(h4b, W2t, b2, lse, (float*)d_out, N, N);

  (void)in_sizes; (void)n_in; (void)out_size; (void)ws_size;
}